// Round 5
// baseline (370.834 us; speedup 1.0000x reference)
//
#include <hip/hip_runtime.h>
#include <hip/hip_bf16.h>
#include <stdint.h>

// LePE windowed attention, MI355X gfx950. Round 9:
//  Rounds 4/6/7/8 all land at 132-142us with very different instruction mixes -> duration is
//  invariant to instruction count => latency-bound; the only lever is waves resident.
//  (256,4) spilled twice because the FULLY-UNROLLED it-loop keeps multi-iteration state live
//  (VGPR_Count=76 arch + ~64 acc > 128). Fix: ROLL the it-loop (#pragma unroll 1):
//  register peak becomes single-iteration peak (~118 <= 128). Q is loaded inside the loop
//  (L2/L3-hot; no qfa[] array -> no runtime indexing -> no scratch). 4 blocks/CU = 16 waves.
//  Numerically bit-identical to round 8.
//  Go/no-go on counters: FETCH ~101MB / WRITE ~65.5MB unchanged = spill-free;
//  WRITE ballooning = third spill strike -> occupancy axis is structurally dead.
//  Kept: half-split K-loop, permlane P-exchange (no p_lds), KSTR=40 pad, cvt_pk bf16
//  conversions, 4-chain ssum, LePE in S^T MFMA shadow, setprio around MFMA.
// Inputs fp32: qkv (3,2,32768,256); conv_w (256,1,3,3); conv_b (256). Output fp32 (2,32768,256).
// Windows: H_SP=32, W_SP=8 -> 256 windows, S=256, heads=8, hd=32. Block per (window,head): grid 2048.

typedef short bf16x8 __attribute__((ext_vector_type(8)));
typedef float f32x4 __attribute__((ext_vector_type(4)));
typedef uint32_t u32x2 __attribute__((ext_vector_type(2)));
typedef uint32_t u32x4 __attribute__((ext_vector_type(4)));

#define KSTR 40    // K rows: 256 x 40 u16 (64B data + 16B pad -> bank-phase rotation 4*(5*row%8))
#define VSTR 264   // Vt rows: 32 x 264 (pad 8: bank rotation + b128 alignment)

__device__ __forceinline__ float bf2f_lo(uint32_t u) {
    union { uint32_t i; float f; } x; x.i = u << 16; return x.f;
}
__device__ __forceinline__ float bf2f_hi(uint32_t u) {
    union { uint32_t i; float f; } x; x.i = u & 0xffff0000u; return x.f;
}
// 2x f32 -> packed bf16 pair (lo=a, hi=b), RNE; compiles to v_cvt_pk_bf16_f32.
__device__ __forceinline__ uint32_t cvt2(float a, float b) {
    union { __hip_bfloat162 h; uint32_t u; } x;
    x.h = __float22bfloat162_rn(make_float2(a, b));
    return x.u;
}

__global__ __launch_bounds__(256, 4)
void lepe_attn(const float* __restrict__ qkv,
               const float* __restrict__ conv_w,
               const float* __restrict__ conv_b,
               float* __restrict__ out)
{
    __shared__ uint16_t k_lds[256 * KSTR];       // 20480 B
    __shared__ uint16_t vt_lds[32 * VSTR];       // 16896 B
    __shared__ float w_lds[288];                 //  1152 B
    __shared__ float b_lds[32];                  //   128 B  => total 38656 B (4x = 155648 <= 160K)

    const int tid  = threadIdx.x;
    const int lane = tid & 63;
    const int wave = tid >> 6;
    const int l15  = lane & 15;
    const int quad = lane >> 4;

    const int blk  = blockIdx.x;
    const int head = blk & 7;
    const int wid  = blk >> 3;
    const int b    = wid >> 7;
    const int rem  = wid & 127;
    const int dpt  = rem >> 2;
    const int nw   = rem & 3;

    const long base_l = (long)dpt * 1024 + nw * 8;
    const int  hc     = head * 32;

    const float c1 = 0.17677669529663687f * 1.4426950408889634f; // SCALE * log2(e)

    // ---- stage K [t][hd] bf16 (pad-40), V^T [hd][t] bf16, LePE weights fp32 ----
    {
        const int  s = tid;
        const long l = base_l + (s >> 3) * 32 + (s & 7);
        const float* kp = qkv + (((long)(2 + b) * 32768 + l) * 256 + hc);
        const float* vp = qkv + (((long)(4 + b) * 32768 + l) * 256 + hc);
        #pragma unroll
        for (int j = 0; j < 8; ++j) {
            float4 kv = ((const float4*)kp)[j];
            u32x2 kb = { cvt2(kv.x, kv.y), cvt2(kv.z, kv.w) };
            *(u32x2*)&k_lds[s * KSTR + j * 4] = kb;
            float4 vv = ((const float4*)vp)[j];
            uint32_t v01 = cvt2(vv.x, vv.y);
            uint32_t v23 = cvt2(vv.z, vv.w);
            vt_lds[(j * 4 + 0) * VSTR + s] = (uint16_t)v01;
            vt_lds[(j * 4 + 1) * VSTR + s] = (uint16_t)(v01 >> 16);
            vt_lds[(j * 4 + 2) * VSTR + s] = (uint16_t)v23;
            vt_lds[(j * 4 + 3) * VSTR + s] = (uint16_t)(v23 >> 16);
        }
        for (int i = tid; i < 288; i += 256) w_lds[i] = conv_w[head * 288 + i];
        if (tid < 32) b_lds[tid] = conv_b[hc + tid];
    }
    __syncthreads();

    // hoist this lane's LePE weights (channels l15 and 16+l15) — loop-invariant
    float wgt[18], bia[2];
    #pragma unroll
    for (int n = 0; n < 2; ++n) {
        #pragma unroll
        for (int i = 0; i < 9; ++i) wgt[n * 9 + i] = w_lds[(n * 16 + l15) * 9 + i];
        bia[n] = b_lds[n * 16 + l15];
    }

    const f32x4 zero4 = {0.f, 0.f, 0.f, 0.f};

    #pragma unroll 1   // ROLLED: register peak = single-iteration peak -> fits 128-reg budget
    for (int it = 0; it < 4; ++it) {
        const int rt = wave * 4 + it;

        // ---- Q load (L2/L3-hot) + convert to MFMA B-fragment, pre-scaled by SCALE*log2e ----
        const int  sq = rt * 16 + l15;
        const long ql = base_l + (sq >> 3) * 32 + (sq & 7);
        const float* qp = qkv + (((long)b * 32768 + ql) * 256 + hc + quad * 8);
        float4 q0 = ((const float4*)qp)[0];
        float4 q1 = ((const float4*)qp)[1];
        u32x4 qp4 = { cvt2(q0.x * c1, q0.y * c1), cvt2(q0.z * c1, q0.w * c1),
                      cvt2(q1.x * c1, q1.y * c1), cvt2(q1.z * c1, q1.w * c1) };
        const bf16x8 qfrag = __builtin_bit_cast(bf16x8, qp4);

        f32x4 accO[2] = {zero4, zero4};
        float ss0 = 0.f, ss1 = 0.f, ss2 = 0.f, ss3 = 0.f;  // 4 independent sum chains
        float lep[2][4];

        #pragma unroll
        for (int half = 0; half < 2; ++half) {
            // ---- S^T = K Q^T, 8 tiles: lane holds S^T[key=16(8h+t)+quad*4+r][query=rt*16+l15]
            f32x4 accS[8];
            __builtin_amdgcn_s_setprio(1);
            #pragma unroll
            for (int t = 0; t < 8; ++t) {
                const int tg = half * 8 + t;
                bf16x8 afrag = *(const bf16x8*)&k_lds[(tg * 16 + l15) * KSTR + quad * 8];
                accS[t] = __builtin_amdgcn_mfma_f32_16x16x32_bf16(afrag, qfrag, zero4, 0, 0, 0);
            }
            __builtin_amdgcn_s_setprio(0);

            // ---- LePE (independent of accS): fills half-0 MFMA drain latency ----
            if (half == 0) {
                const int hrow = rt * 2 + (quad >> 1);
                const int wsel = quad & 1;
                #pragma unroll
                for (int n = 0; n < 2; ++n) {
                    const int d = n * 16 + l15;
                    float lep0 = bia[n], lep1 = bia[n], lep2 = bia[n], lep3 = bia[n];
                    #pragma unroll
                    for (int dy = 0; dy < 3; ++dy) {
                        const int hh = hrow + dy - 1;
                        float e0 = 0.f, e1 = 0.f, e2 = 0.f, e3 = 0.f, e4 = 0.f, e5 = 0.f;
                        if (hh >= 0 && hh < 32) {
                            uint4 rv = *(const uint4*)&vt_lds[d * VSTR + hh * 8];
                            float c0 = bf2f_lo(rv.x), c1v = bf2f_hi(rv.x);
                            float c2 = bf2f_lo(rv.y), c3 = bf2f_hi(rv.y);
                            float c4 = bf2f_lo(rv.z), c5 = bf2f_hi(rv.z);
                            float c6 = bf2f_lo(rv.w), c7 = bf2f_hi(rv.w);
                            e0 = wsel ? c3 : 0.f;  e1 = wsel ? c4 : c0;
                            e2 = wsel ? c5 : c1v;  e3 = wsel ? c6 : c2;
                            e4 = wsel ? c7 : c3;   e5 = wsel ? 0.f : c4;
                        }
                        const float w0 = wgt[n * 9 + dy * 3 + 0];
                        const float w1 = wgt[n * 9 + dy * 3 + 1];
                        const float w2 = wgt[n * 9 + dy * 3 + 2];
                        lep0 = fmaf(w0, e0, fmaf(w1, e1, fmaf(w2, e2, lep0)));
                        lep1 = fmaf(w0, e1, fmaf(w1, e2, fmaf(w2, e3, lep1)));
                        lep2 = fmaf(w0, e2, fmaf(w1, e3, fmaf(w2, e4, lep2)));
                        lep3 = fmaf(w0, e3, fmaf(w1, e4, fmaf(w2, e5, lep3)));
                    }
                    lep[n][0] = lep0; lep[n][1] = lep1; lep[n][2] = lep2; lep[n][3] = lep3;
                }
            }

            // ---- softmax (max-free) + pack P to bf16 via cvt_pk; accS dies into pkl/pkh ----
            uint32_t pkl[8], pkh[8];
            #pragma unroll
            for (int t = 0; t < 8; ++t) {
                float p0 = exp2f(accS[t][0]);
                float p1 = exp2f(accS[t][1]);
                float p2 = exp2f(accS[t][2]);
                float p3 = exp2f(accS[t][3]);
                ss0 += p0; ss1 += p1; ss2 += p2; ss3 += p3;
                pkl[t] = cvt2(p0, p1);
                pkh[t] = cvt2(p2, p3);
            }

            // ---- PV: in-register quad exchange (permlane32/16_swap), 4 column pairs ----
            __builtin_amdgcn_s_setprio(1);
            #pragma unroll
            for (int cc = 0; cc < 4; ++cc) {
                uint32_t a0 = pkl[2 * cc], a1 = pkl[2 * cc + 1];
                uint32_t b0 = pkh[2 * cc], b1 = pkh[2 * cc + 1];
                asm("v_permlane32_swap_b32 %0, %1" : "+v"(a0), "+v"(a1));
                asm("v_permlane32_swap_b32 %0, %1" : "+v"(b0), "+v"(b1));
                asm("v_permlane16_swap_b32 %0, %1" : "+v"(a0), "+v"(a1));
                asm("v_permlane16_swap_b32 %0, %1" : "+v"(b0), "+v"(b1));
                u32x4 pv = {a0, b0, a1, b1};
                bf16x8 pa = __builtin_bit_cast(bf16x8, pv);
                const int kb = (half * 4 + cc) * 32 + quad * 8;
                bf16x8 vb0 = *(const bf16x8*)&vt_lds[l15 * VSTR + kb];
                accO[0] = __builtin_amdgcn_mfma_f32_16x16x32_bf16(pa, vb0, accO[0], 0, 0, 0);
                bf16x8 vb1 = *(const bf16x8*)&vt_lds[(16 + l15) * VSTR + kb];
                accO[1] = __builtin_amdgcn_mfma_f32_16x16x32_bf16(pa, vb1, accO[1], 0, 0, 0);
            }
            __builtin_amdgcn_s_setprio(0);
        }

        // ---- softmax denominator reduce (all 256 keys seen) ----
        float ssum = (ss0 + ss1) + (ss2 + ss3);
        ssum += __shfl_xor(ssum, 16);
        ssum += __shfl_xor(ssum, 32);
        const float linv = __builtin_amdgcn_rcpf(ssum);
        // output row r of this lane is query quad*4+r; its sum lives at lane l15'=quad*4+r
        float linv4[4];
        #pragma unroll
        for (int r = 0; r < 4; ++r) linv4[r] = __shfl(linv, quad * 4 + r);

        // ---- epilogue: normalize, add LePE, store ----
        #pragma unroll
        for (int n = 0; n < 2; ++n) {
            const int d = n * 16 + l15;
            #pragma unroll
            for (int r = 0; r < 4; ++r) {
                const int s  = rt * 16 + quad * 4 + r;
                const int h  = s >> 3, w_ = s & 7;
                const long ol = base_l + h * 32 + w_;
                out[((long)b * 32768 + ol) * 256 + hc + d] = accO[n][r] * linv4[r] + lep[n][r];
            }
        }
    }
}

extern "C" void kernel_launch(void* const* d_in, const int* in_sizes, int n_in,
                              void* d_out, int out_size, void* d_ws, size_t ws_size,
                              hipStream_t stream)
{
    const float* qkv = (const float*)d_in[0];
    const float* cw  = (const float*)d_in[1];
    const float* cb  = (const float*)d_in[2];
    float* o = (float*)d_out;
    lepe_attn<<<2048, 256, 0, stream>>>(qkv, cw, cb, o);
}

// Round 8
// 335.699 us; speedup vs baseline: 1.1047x; 1.1047x over previous
//
#include <hip/hip_runtime.h>
#include <hip/hip_bf16.h>
#include <stdint.h>

// LePE windowed attention, MI355X gfx950. Round 12 (= round 10/11 resubmitted; two infra
// failures — "container failed twice" is an acquisition error, produced before compile/run;
// source audited: no construct differs in kind from kernels that ran clean in r4-r9).
//  Hypothesis (still untested): r5/r7/r9 spilled at (256,4) because ARCH-VGPR demand > 64
//  (allocator pins arch side to 64 under the 128-reg MFMA budget). This version cuts arch
//  pressure to ~55:
//  - LePE fully in the epilogue; wgt/bia NOT hoisted (read from w_lds there): -28 arch.
//  - Quarter-split K-loop (4 tiles/quarter, #pragma unroll 1): live acc = accS[4]+accO[2]=24,
//    pk=8: -8 arch; no cross-quarter scheduling overlap possible.
//  - it-loop rolled (#pragma unroll 1), Q loaded in-loop (L2/L3-hot).
//  Numerically identical ops in identical order vs r8.
//  Pre-committed fallback: spill signature (WRITE >> 66MB) or another failure -> revert to r8
//  structure permanently; occupancy axis closed.
// Inputs fp32: qkv (3,2,32768,256); conv_w (256,1,3,3); conv_b (256). Output fp32 (2,32768,256).
// Windows: H_SP=32, W_SP=8 -> 256 windows, S=256, heads=8, hd=32. Block per (window,head): grid 2048.

typedef short bf16x8 __attribute__((ext_vector_type(8)));
typedef float f32x4 __attribute__((ext_vector_type(4)));
typedef uint32_t u32x2 __attribute__((ext_vector_type(2)));
typedef uint32_t u32x4 __attribute__((ext_vector_type(4)));

#define KSTR 40    // K rows: 256 x 40 u16 (64B data + 16B pad -> bank-phase rotation 4*(5*row%8))
#define VSTR 264   // Vt rows: 32 x 264 (pad 8: bank rotation + b128 alignment)

__device__ __forceinline__ float bf2f_lo(uint32_t u) {
    union { uint32_t i; float f; } x; x.i = u << 16; return x.f;
}
__device__ __forceinline__ float bf2f_hi(uint32_t u) {
    union { uint32_t i; float f; } x; x.i = u & 0xffff0000u; return x.f;
}
// 2x f32 -> packed bf16 pair (lo=a, hi=b), RNE; compiles to v_cvt_pk_bf16_f32.
__device__ __forceinline__ uint32_t cvt2(float a, float b) {
    union { __hip_bfloat162 h; uint32_t u; } x;
    x.h = __float22bfloat162_rn(make_float2(a, b));
    return x.u;
}

__global__ __launch_bounds__(256, 4)
void lepe_attn(const float* __restrict__ qkv,
               const float* __restrict__ conv_w,
               const float* __restrict__ conv_b,
               float* __restrict__ out)
{
    __shared__ uint16_t k_lds[256 * KSTR];       // 20480 B
    __shared__ uint16_t vt_lds[32 * VSTR];       // 16896 B
    __shared__ float w_lds[288];                 //  1152 B
    __shared__ float b_lds[32];                  //   128 B  => total 38656 B (4x <= 160K)

    const int tid  = threadIdx.x;
    const int lane = tid & 63;
    const int wave = tid >> 6;
    const int l15  = lane & 15;
    const int quad = lane >> 4;

    const int blk  = blockIdx.x;
    const int head = blk & 7;
    const int wid  = blk >> 3;
    const int b    = wid >> 7;
    const int rem  = wid & 127;
    const int dpt  = rem >> 2;
    const int nw   = rem & 3;

    const long base_l = (long)dpt * 1024 + nw * 8;
    const int  hc     = head * 32;

    const float c1 = 0.17677669529663687f * 1.4426950408889634f; // SCALE * log2(e)

    // ---- stage K [t][hd] bf16 (pad-40), V^T [hd][t] bf16, LePE weights fp32 ----
    {
        const int  s = tid;
        const long l = base_l + (s >> 3) * 32 + (s & 7);
        const float* kp = qkv + (((long)(2 + b) * 32768 + l) * 256 + hc);
        const float* vp = qkv + (((long)(4 + b) * 32768 + l) * 256 + hc);
        #pragma unroll
        for (int j = 0; j < 8; ++j) {
            float4 kv = ((const float4*)kp)[j];
            u32x2 kb = { cvt2(kv.x, kv.y), cvt2(kv.z, kv.w) };
            *(u32x2*)&k_lds[s * KSTR + j * 4] = kb;
            float4 vv = ((const float4*)vp)[j];
            uint32_t v01 = cvt2(vv.x, vv.y);
            uint32_t v23 = cvt2(vv.z, vv.w);
            vt_lds[(j * 4 + 0) * VSTR + s] = (uint16_t)v01;
            vt_lds[(j * 4 + 1) * VSTR + s] = (uint16_t)(v01 >> 16);
            vt_lds[(j * 4 + 2) * VSTR + s] = (uint16_t)v23;
            vt_lds[(j * 4 + 3) * VSTR + s] = (uint16_t)(v23 >> 16);
        }
        for (int i = tid; i < 288; i += 256) w_lds[i] = conv_w[head * 288 + i];
        if (tid < 32) b_lds[tid] = conv_b[hc + tid];
    }
    __syncthreads();

    const f32x4 zero4 = {0.f, 0.f, 0.f, 0.f};

    #pragma unroll 1   // ROLLED: keep per-iteration register peak only
    for (int it = 0; it < 4; ++it) {
        const int rt = wave * 4 + it;

        // ---- Q load (L2/L3-hot) + convert to MFMA B-fragment, pre-scaled by SCALE*log2e ----
        const int  sq = rt * 16 + l15;
        const long ql = base_l + (sq >> 3) * 32 + (sq & 7);
        const float* qp = qkv + (((long)b * 32768 + ql) * 256 + hc + quad * 8);
        float4 q0 = ((const float4*)qp)[0];
        float4 q1 = ((const float4*)qp)[1];
        u32x4 qp4 = { cvt2(q0.x * c1, q0.y * c1), cvt2(q0.z * c1, q0.w * c1),
                      cvt2(q1.x * c1, q1.y * c1), cvt2(q1.z * c1, q1.w * c1) };
        const bf16x8 qfrag = __builtin_bit_cast(bf16x8, qp4);

        f32x4 accO[2] = {zero4, zero4};
        float ss0 = 0.f, ss1 = 0.f, ss2 = 0.f, ss3 = 0.f;  // 4 independent sum chains

        #pragma unroll 1   // quarter-split: live acc = accS[4]+accO[2]=24, pk=8
        for (int qt = 0; qt < 4; ++qt) {
            // ---- S^T = K Q^T, 4 tiles: lane holds S^T[key=16(4qt+t)+quad*4+r][query=rt*16+l15]
            f32x4 accS[4];
            __builtin_amdgcn_s_setprio(1);
            #pragma unroll
            for (int t = 0; t < 4; ++t) {
                const int tg = qt * 4 + t;
                bf16x8 afrag = *(const bf16x8*)&k_lds[(tg * 16 + l15) * KSTR + quad * 8];
                accS[t] = __builtin_amdgcn_mfma_f32_16x16x32_bf16(afrag, qfrag, zero4, 0, 0, 0);
            }
            __builtin_amdgcn_s_setprio(0);

            // ---- softmax (max-free) + pack P to bf16 via cvt_pk; accS dies into pkl/pkh ----
            uint32_t pkl[4], pkh[4];
            #pragma unroll
            for (int t = 0; t < 4; ++t) {
                float p0 = exp2f(accS[t][0]);
                float p1 = exp2f(accS[t][1]);
                float p2 = exp2f(accS[t][2]);
                float p3 = exp2f(accS[t][3]);
                ss0 += p0; ss1 += p1; ss2 += p2; ss3 += p3;
                pkl[t] = cvt2(p0, p1);
                pkh[t] = cvt2(p2, p3);
            }

            // ---- PV: in-register quad exchange (permlane32/16_swap), 2 column pairs ----
            __builtin_amdgcn_s_setprio(1);
            #pragma unroll
            for (int c = 0; c < 2; ++c) {
                uint32_t a0 = pkl[2 * c], a1 = pkl[2 * c + 1];
                uint32_t b0 = pkh[2 * c], b1 = pkh[2 * c + 1];
                asm("v_permlane32_swap_b32 %0, %1" : "+v"(a0), "+v"(a1));
                asm("v_permlane32_swap_b32 %0, %1" : "+v"(b0), "+v"(b1));
                asm("v_permlane16_swap_b32 %0, %1" : "+v"(a0), "+v"(a1));
                asm("v_permlane16_swap_b32 %0, %1" : "+v"(b0), "+v"(b1));
                u32x4 pv = {a0, b0, a1, b1};
                bf16x8 pa = __builtin_bit_cast(bf16x8, pv);
                const int kb = (qt * 2 + c) * 32 + quad * 8;
                bf16x8 vb0 = *(const bf16x8*)&vt_lds[l15 * VSTR + kb];
                accO[0] = __builtin_amdgcn_mfma_f32_16x16x32_bf16(pa, vb0, accO[0], 0, 0, 0);
                bf16x8 vb1 = *(const bf16x8*)&vt_lds[(16 + l15) * VSTR + kb];
                accO[1] = __builtin_amdgcn_mfma_f32_16x16x32_bf16(pa, vb1, accO[1], 0, 0, 0);
            }
            __builtin_amdgcn_s_setprio(0);
        }

        // ---- softmax denominator reduce (all 256 keys seen) ----
        float ssum = (ss0 + ss1) + (ss2 + ss3);
        ssum += __shfl_xor(ssum, 16);
        ssum += __shfl_xor(ssum, 32);
        const float linv = __builtin_amdgcn_rcpf(ssum);
        // output row r of this lane is query quad*4+r; its sum lives at lane l15'=quad*4+r
        float linv4[4];
        #pragma unroll
        for (int r = 0; r < 4; ++r) linv4[r] = __shfl(linv, quad * 4 + r);

        // ---- epilogue: LePE (weights read from LDS here; not register-resident) + store ----
        const int hrow = rt * 2 + (quad >> 1);
        const int wsel = quad & 1;
        #pragma unroll
        for (int n = 0; n < 2; ++n) {
            const int d = n * 16 + l15;
            const float* wrow = &w_lds[(n * 16 + l15) * 9];
            float lep0, lep1, lep2, lep3;
            lep0 = lep1 = lep2 = lep3 = b_lds[n * 16 + l15];
            #pragma unroll
            for (int dy = 0; dy < 3; ++dy) {
                const int hh = hrow + dy - 1;
                float e0 = 0.f, e1 = 0.f, e2 = 0.f, e3 = 0.f, e4 = 0.f, e5 = 0.f;
                if (hh >= 0 && hh < 32) {
                    uint4 rv = *(const uint4*)&vt_lds[d * VSTR + hh * 8];
                    float c0 = bf2f_lo(rv.x), c1v = bf2f_hi(rv.x);
                    float c2 = bf2f_lo(rv.y), c3 = bf2f_hi(rv.y);
                    float c4 = bf2f_lo(rv.z), c5 = bf2f_hi(rv.z);
                    float c6 = bf2f_lo(rv.w), c7 = bf2f_hi(rv.w);
                    e0 = wsel ? c3 : 0.f;  e1 = wsel ? c4 : c0;
                    e2 = wsel ? c5 : c1v;  e3 = wsel ? c6 : c2;
                    e4 = wsel ? c7 : c3;   e5 = wsel ? 0.f : c4;
                }
                const float w0 = wrow[dy * 3 + 0];
                const float w1 = wrow[dy * 3 + 1];
                const float w2 = wrow[dy * 3 + 2];
                lep0 = fmaf(w0, e0, fmaf(w1, e1, fmaf(w2, e2, lep0)));
                lep1 = fmaf(w0, e1, fmaf(w1, e2, fmaf(w2, e3, lep1)));
                lep2 = fmaf(w0, e2, fmaf(w1, e3, fmaf(w2, e4, lep2)));
                lep3 = fmaf(w0, e3, fmaf(w1, e4, fmaf(w2, e5, lep3)));
            }
            const float lp[4] = {lep0, lep1, lep2, lep3};
            #pragma unroll
            for (int r = 0; r < 4; ++r) {
                const int s  = rt * 16 + quad * 4 + r;
                const int h  = s >> 3, w_ = s & 7;
                const long ol = base_l + h * 32 + w_;
                out[((long)b * 32768 + ol) * 256 + hc + d] = accO[n][r] * linv4[r] + lp[r];
            }
        }
    }
}

extern "C" void kernel_launch(void* const* d_in, const int* in_sizes, int n_in,
                              void* d_out, int out_size, void* d_ws, size_t ws_size,
                              hipStream_t stream)
{
    const float* qkv = (const float*)d_in[0];
    const float* cw  = (const float*)d_in[1];
    const float* cb  = (const float*)d_in[2];
    float* o = (float*)d_out;
    lepe_attn<<<2048, 256, 0, stream>>>(qkv, cw, cb, o);
}

// Round 9
// 321.593 us; speedup vs baseline: 1.1531x; 1.0439x over previous
//
#include <hip/hip_runtime.h>
#include <hip/hip_bf16.h>
#include <stdint.h>

// LePE windowed attention, MI355X gfx950. Round 13:
//  r12 answered the occupancy question: +33% waves resident -> only -3% time. Occupancy axis
//  closed. VALU (42%) is the busiest pipe; per-SIMD math shows ~8K VALU insts/thread — ~2x the
//  source census, gap = ocml exp2f expansion (256 exps/thread, no fast-math). Changes:
//  1) exp2f -> __builtin_amdgcn_exp2f (raw v_exp_f32). Range safe (|S*log2e| << 87), +-1 ulp.
//  2) XCD co-schedule swizzle: blk = chunk*64 + head*8 + wlow, wid = chunk*8 + wlow.
//     The 8 head-blocks of a window share (mod 8) id class AND are <64 ids apart -> same XCD,
//     co-resident -> window rows hit per-XCD L2 (~200cy) instead of L3 (~500-900cy).
//  3) Q software-pipelined across the ROLLED it-loop (convert current, then issue next loads).
//  Go/no-go: WRITE ~66MB = spill-free (VGPR 52 -> ~60 expected). If <5% total: structure is
//  converged; next move is per-wave ILP restructure, not peephole.
//  Kept from r12: (256,4) 4 blocks/CU, LePE in epilogue (weights from LDS), quarter-split
//  rolled K-loop, permlane P-exchange, KSTR=40 pad, cvt_pk bf16, 4-chain ssum, setprio.
// Inputs fp32: qkv (3,2,32768,256); conv_w (256,1,3,3); conv_b (256). Output fp32 (2,32768,256).
// Windows: H_SP=32, W_SP=8 -> 256 windows, S=256, heads=8, hd=32. Block per (window,head): grid 2048.

typedef short bf16x8 __attribute__((ext_vector_type(8)));
typedef float f32x4 __attribute__((ext_vector_type(4)));
typedef uint32_t u32x2 __attribute__((ext_vector_type(2)));
typedef uint32_t u32x4 __attribute__((ext_vector_type(4)));

#define KSTR 40    // K rows: 256 x 40 u16 (64B data + 16B pad -> bank-phase rotation 4*(5*row%8))
#define VSTR 264   // Vt rows: 32 x 264 (pad 8: bank rotation + b128 alignment)

__device__ __forceinline__ float bf2f_lo(uint32_t u) {
    union { uint32_t i; float f; } x; x.i = u << 16; return x.f;
}
__device__ __forceinline__ float bf2f_hi(uint32_t u) {
    union { uint32_t i; float f; } x; x.i = u & 0xffff0000u; return x.f;
}
// 2x f32 -> packed bf16 pair (lo=a, hi=b), RNE; compiles to v_cvt_pk_bf16_f32.
__device__ __forceinline__ uint32_t cvt2(float a, float b) {
    union { __hip_bfloat162 h; uint32_t u; } x;
    x.h = __float22bfloat162_rn(make_float2(a, b));
    return x.u;
}

__global__ __launch_bounds__(256, 4)
void lepe_attn(const float* __restrict__ qkv,
               const float* __restrict__ conv_w,
               const float* __restrict__ conv_b,
               float* __restrict__ out)
{
    __shared__ uint16_t k_lds[256 * KSTR];       // 20480 B
    __shared__ uint16_t vt_lds[32 * VSTR];       // 16896 B
    __shared__ float w_lds[288];                 //  1152 B
    __shared__ float b_lds[32];                  //   128 B  => total 38656 B (4x <= 160K)

    const int tid  = threadIdx.x;
    const int lane = tid & 63;
    const int wave = tid >> 6;
    const int l15  = lane & 15;
    const int quad = lane >> 4;

    // XCD co-schedule swizzle: blk = chunk*64 + head*8 + wlow; wid = chunk*8 + wlow.
    // Same-window head-blocks: ids differ by 8 (same XCD slot under mod-8 round-robin) and are
    // dispatched within 64 ids of each other (co-resident) -> shared window rows hit L2.
    const int blk  = blockIdx.x;
    const int head = (blk >> 3) & 7;
    const int wid  = ((blk >> 6) << 3) | (blk & 7);
    const int b    = wid >> 7;
    const int rem  = wid & 127;
    const int dpt  = rem >> 2;
    const int nw   = rem & 3;

    const long base_l = (long)dpt * 1024 + nw * 8;
    const int  hc     = head * 32;

    const float c1 = 0.17677669529663687f * 1.4426950408889634f; // SCALE * log2(e)

    // ---- stage K [t][hd] bf16 (pad-40), V^T [hd][t] bf16, LePE weights fp32 ----
    {
        const int  s = tid;
        const long l = base_l + (s >> 3) * 32 + (s & 7);
        const float* kp = qkv + (((long)(2 + b) * 32768 + l) * 256 + hc);
        const float* vp = qkv + (((long)(4 + b) * 32768 + l) * 256 + hc);
        #pragma unroll
        for (int j = 0; j < 8; ++j) {
            float4 kv = ((const float4*)kp)[j];
            u32x2 kb = { cvt2(kv.x, kv.y), cvt2(kv.z, kv.w) };
            *(u32x2*)&k_lds[s * KSTR + j * 4] = kb;
            float4 vv = ((const float4*)vp)[j];
            uint32_t v01 = cvt2(vv.x, vv.y);
            uint32_t v23 = cvt2(vv.z, vv.w);
            vt_lds[(j * 4 + 0) * VSTR + s] = (uint16_t)v01;
            vt_lds[(j * 4 + 1) * VSTR + s] = (uint16_t)(v01 >> 16);
            vt_lds[(j * 4 + 2) * VSTR + s] = (uint16_t)v23;
            vt_lds[(j * 4 + 3) * VSTR + s] = (uint16_t)(v23 >> 16);
        }
        for (int i = tid; i < 288; i += 256) w_lds[i] = conv_w[head * 288 + i];
        if (tid < 32) b_lds[tid] = conv_b[hc + tid];
    }
    __syncthreads();

    const f32x4 zero4 = {0.f, 0.f, 0.f, 0.f};

    // ---- Q software pipeline: load iteration 0 before the rolled loop ----
    float4 qA0, qA1;
    {
        const int  sq = (wave * 4 + 0) * 16 + l15;
        const long ql = base_l + (sq >> 3) * 32 + (sq & 7);
        const float* qp = qkv + (((long)b * 32768 + ql) * 256 + hc + quad * 8);
        qA0 = ((const float4*)qp)[0];
        qA1 = ((const float4*)qp)[1];
    }

    #pragma unroll 1   // ROLLED: keep per-iteration register peak only
    for (int it = 0; it < 4; ++it) {
        const int rt = wave * 4 + it;

        // ---- convert current Q (pre-scaled by SCALE*log2e), then prefetch next Q ----
        u32x4 qp4 = { cvt2(qA0.x * c1, qA0.y * c1), cvt2(qA0.z * c1, qA0.w * c1),
                      cvt2(qA1.x * c1, qA1.y * c1), cvt2(qA1.z * c1, qA1.w * c1) };
        const bf16x8 qfrag = __builtin_bit_cast(bf16x8, qp4);
        {
            const int  itn = (it < 3) ? it + 1 : 3;   // it=3 reloads (L2-hot, harmless)
            const int  sq  = (wave * 4 + itn) * 16 + l15;
            const long ql  = base_l + (sq >> 3) * 32 + (sq & 7);
            const float* qp = qkv + (((long)b * 32768 + ql) * 256 + hc + quad * 8);
            qA0 = ((const float4*)qp)[0];
            qA1 = ((const float4*)qp)[1];
        }

        f32x4 accO[2] = {zero4, zero4};
        float ss0 = 0.f, ss1 = 0.f, ss2 = 0.f, ss3 = 0.f;  // 4 independent sum chains

        #pragma unroll 1   // quarter-split: live acc = accS[4]+accO[2]=24, pk=8
        for (int qt = 0; qt < 4; ++qt) {
            // ---- S^T = K Q^T, 4 tiles: lane holds S^T[key=16(4qt+t)+quad*4+r][query=rt*16+l15]
            f32x4 accS[4];
            __builtin_amdgcn_s_setprio(1);
            #pragma unroll
            for (int t = 0; t < 4; ++t) {
                const int tg = qt * 4 + t;
                bf16x8 afrag = *(const bf16x8*)&k_lds[(tg * 16 + l15) * KSTR + quad * 8];
                accS[t] = __builtin_amdgcn_mfma_f32_16x16x32_bf16(afrag, qfrag, zero4, 0, 0, 0);
            }
            __builtin_amdgcn_s_setprio(0);

            // ---- softmax (max-free): raw v_exp_f32; pack P to bf16 via cvt_pk ----
            uint32_t pkl[4], pkh[4];
            #pragma unroll
            for (int t = 0; t < 4; ++t) {
                float p0 = __builtin_amdgcn_exp2f(accS[t][0]);
                float p1 = __builtin_amdgcn_exp2f(accS[t][1]);
                float p2 = __builtin_amdgcn_exp2f(accS[t][2]);
                float p3 = __builtin_amdgcn_exp2f(accS[t][3]);
                ss0 += p0; ss1 += p1; ss2 += p2; ss3 += p3;
                pkl[t] = cvt2(p0, p1);
                pkh[t] = cvt2(p2, p3);
            }

            // ---- PV: in-register quad exchange (permlane32/16_swap), 2 column pairs ----
            __builtin_amdgcn_s_setprio(1);
            #pragma unroll
            for (int c = 0; c < 2; ++c) {
                uint32_t a0 = pkl[2 * c], a1 = pkl[2 * c + 1];
                uint32_t b0 = pkh[2 * c], b1 = pkh[2 * c + 1];
                asm("v_permlane32_swap_b32 %0, %1" : "+v"(a0), "+v"(a1));
                asm("v_permlane32_swap_b32 %0, %1" : "+v"(b0), "+v"(b1));
                asm("v_permlane16_swap_b32 %0, %1" : "+v"(a0), "+v"(a1));
                asm("v_permlane16_swap_b32 %0, %1" : "+v"(b0), "+v"(b1));
                u32x4 pv = {a0, b0, a1, b1};
                bf16x8 pa = __builtin_bit_cast(bf16x8, pv);
                const int kb = (qt * 2 + c) * 32 + quad * 8;
                bf16x8 vb0 = *(const bf16x8*)&vt_lds[l15 * VSTR + kb];
                accO[0] = __builtin_amdgcn_mfma_f32_16x16x32_bf16(pa, vb0, accO[0], 0, 0, 0);
                bf16x8 vb1 = *(const bf16x8*)&vt_lds[(16 + l15) * VSTR + kb];
                accO[1] = __builtin_amdgcn_mfma_f32_16x16x32_bf16(pa, vb1, accO[1], 0, 0, 0);
            }
            __builtin_amdgcn_s_setprio(0);
        }

        // ---- softmax denominator reduce (all 256 keys seen) ----
        float ssum = (ss0 + ss1) + (ss2 + ss3);
        ssum += __shfl_xor(ssum, 16);
        ssum += __shfl_xor(ssum, 32);
        const float linv = __builtin_amdgcn_rcpf(ssum);
        // output row r of this lane is query quad*4+r; its sum lives at lane l15'=quad*4+r
        float linv4[4];
        #pragma unroll
        for (int r = 0; r < 4; ++r) linv4[r] = __shfl(linv, quad * 4 + r);

        // ---- epilogue: LePE (weights read from LDS here; not register-resident) + store ----
        const int hrow = rt * 2 + (quad >> 1);
        const int wsel = quad & 1;
        #pragma unroll
        for (int n = 0; n < 2; ++n) {
            const int d = n * 16 + l15;
            const float* wrow = &w_lds[(n * 16 + l15) * 9];
            float lep0, lep1, lep2, lep3;
            lep0 = lep1 = lep2 = lep3 = b_lds[n * 16 + l15];
            #pragma unroll
            for (int dy = 0; dy < 3; ++dy) {
                const int hh = hrow + dy - 1;
                float e0 = 0.f, e1 = 0.f, e2 = 0.f, e3 = 0.f, e4 = 0.f, e5 = 0.f;
                if (hh >= 0 && hh < 32) {
                    uint4 rv = *(const uint4*)&vt_lds[d * VSTR + hh * 8];
                    float c0 = bf2f_lo(rv.x), c1v = bf2f_hi(rv.x);
                    float c2 = bf2f_lo(rv.y), c3 = bf2f_hi(rv.y);
                    float c4 = bf2f_lo(rv.z), c5 = bf2f_hi(rv.z);
                    float c6 = bf2f_lo(rv.w), c7 = bf2f_hi(rv.w);
                    e0 = wsel ? c3 : 0.f;  e1 = wsel ? c4 : c0;
                    e2 = wsel ? c5 : c1v;  e3 = wsel ? c6 : c2;
                    e4 = wsel ? c7 : c3;   e5 = wsel ? 0.f : c4;
                }
                const float w0 = wrow[dy * 3 + 0];
                const float w1 = wrow[dy * 3 + 1];
                const float w2 = wrow[dy * 3 + 2];
                lep0 = fmaf(w0, e0, fmaf(w1, e1, fmaf(w2, e2, lep0)));
                lep1 = fmaf(w0, e1, fmaf(w1, e2, fmaf(w2, e3, lep1)));
                lep2 = fmaf(w0, e2, fmaf(w1, e3, fmaf(w2, e4, lep2)));
                lep3 = fmaf(w0, e3, fmaf(w1, e4, fmaf(w2, e5, lep3)));
            }
            const float lp[4] = {lep0, lep1, lep2, lep3};
            #pragma unroll
            for (int r = 0; r < 4; ++r) {
                const int s  = rt * 16 + quad * 4 + r;
                const int h  = s >> 3, w_ = s & 7;
                const long ol = base_l + h * 32 + w_;
                out[((long)b * 32768 + ol) * 256 + hc + d] = accO[n][r] * linv4[r] + lp[r];
            }
        }
    }
}

extern "C" void kernel_launch(void* const* d_in, const int* in_sizes, int n_in,
                              void* d_out, int out_size, void* d_ws, size_t ws_size,
                              hipStream_t stream)
{
    const float* qkv = (const float*)d_in[0];
    const float* cw  = (const float*)d_in[1];
    const float* cb  = (const float*)d_in[2];
    float* o = (float*)d_out;
    lepe_attn<<<2048, 256, 0, stream>>>(qkv, cw, cb, o);
}

// Round 10
// 320.155 us; speedup vs baseline: 1.1583x; 1.0045x over previous
//
#include <hip/hip_runtime.h>
#include <hip/hip_bf16.h>
#include <stdint.h>

// LePE windowed attention, MI355X gfx950. Round 14:
//  r13 WIN (~130 -> ~116us; bench 335.7 -> 321.6): raw v_exp_f32 + XCD co-schedule + Q pipeline.
//  FETCH ~100MB / WRITE ~67MB are now exactly minimal -> memory floor ~27us, MFMA floor ~8us;
//  at ~116us we are latency-bound on the serial quarter chain:
//  ds_read -> S-MFMA -> exp/pack(VALU) -> permlane -> PV-MFMA(dependent accO chain), x4.
//  Change: 2-stage ping-pong pipeline across quarters (static named buffers sA/sB, rule-#20
//  safe, zero register copies): S(0); then [S(1); PV(0); S(2); PV(1)]; [S(3); PV(2); PV(3)].
//  Each quarter's exp/PV overlaps the next quarter's independent S-MFMAs (VALU hides under
//  MFMA issue; dependent accO chain interleaves with independent S tiles).
//  PV/ssum order over quarters unchanged -> bit-identical numerics.
//  Register audit: acc = sA16+sB16+accO8 = 40; arch ~55-60 -> (256,4) should stay spill-free.
//  Go/no-go: WRITE ~67MB / VGPR <= ~64; WRITE ballooning -> revert ping-pong.
//  Kept: (256,4), rolled it-loop, LePE in epilogue (weights from LDS), permlane P-exchange,
//  KSTR=40 pad, cvt_pk bf16, raw exp2, 4-chain ssum, XCD swizzle, Q software pipeline, setprio.
// Inputs fp32: qkv (3,2,32768,256); conv_w (256,1,3,3); conv_b (256). Output fp32 (2,32768,256).
// Windows: H_SP=32, W_SP=8 -> 256 windows, S=256, heads=8, hd=32. Block per (window,head): grid 2048.

typedef short bf16x8 __attribute__((ext_vector_type(8)));
typedef float f32x4 __attribute__((ext_vector_type(4)));
typedef uint32_t u32x2 __attribute__((ext_vector_type(2)));
typedef uint32_t u32x4 __attribute__((ext_vector_type(4)));

#define KSTR 40    // K rows: 256 x 40 u16 (64B data + 16B pad -> bank-phase rotation 4*(5*row%8))
#define VSTR 264   // Vt rows: 32 x 264 (pad 8: bank rotation + b128 alignment)

__device__ __forceinline__ float bf2f_lo(uint32_t u) {
    union { uint32_t i; float f; } x; x.i = u << 16; return x.f;
}
__device__ __forceinline__ float bf2f_hi(uint32_t u) {
    union { uint32_t i; float f; } x; x.i = u & 0xffff0000u; return x.f;
}
// 2x f32 -> packed bf16 pair (lo=a, hi=b), RNE; compiles to v_cvt_pk_bf16_f32.
__device__ __forceinline__ uint32_t cvt2(float a, float b) {
    union { __hip_bfloat162 h; uint32_t u; } x;
    x.h = __float22bfloat162_rn(make_float2(a, b));
    return x.u;
}

__global__ __launch_bounds__(256, 4)
void lepe_attn(const float* __restrict__ qkv,
               const float* __restrict__ conv_w,
               const float* __restrict__ conv_b,
               float* __restrict__ out)
{
    __shared__ uint16_t k_lds[256 * KSTR];       // 20480 B
    __shared__ uint16_t vt_lds[32 * VSTR];       // 16896 B
    __shared__ float w_lds[288];                 //  1152 B
    __shared__ float b_lds[32];                  //   128 B  => total 38656 B (4x <= 160K)

    const int tid  = threadIdx.x;
    const int lane = tid & 63;
    const int wave = tid >> 6;
    const int l15  = lane & 15;
    const int quad = lane >> 4;

    // XCD co-schedule swizzle: blk = chunk*64 + head*8 + wlow; wid = chunk*8 + wlow.
    const int blk  = blockIdx.x;
    const int head = (blk >> 3) & 7;
    const int wid  = ((blk >> 6) << 3) | (blk & 7);
    const int b    = wid >> 7;
    const int rem  = wid & 127;
    const int dpt  = rem >> 2;
    const int nw   = rem & 3;

    const long base_l = (long)dpt * 1024 + nw * 8;
    const int  hc     = head * 32;

    const float c1 = 0.17677669529663687f * 1.4426950408889634f; // SCALE * log2(e)

    // ---- stage K [t][hd] bf16 (pad-40), V^T [hd][t] bf16, LePE weights fp32 ----
    {
        const int  s = tid;
        const long l = base_l + (s >> 3) * 32 + (s & 7);
        const float* kp = qkv + (((long)(2 + b) * 32768 + l) * 256 + hc);
        const float* vp = qkv + (((long)(4 + b) * 32768 + l) * 256 + hc);
        #pragma unroll
        for (int j = 0; j < 8; ++j) {
            float4 kv = ((const float4*)kp)[j];
            u32x2 kb = { cvt2(kv.x, kv.y), cvt2(kv.z, kv.w) };
            *(u32x2*)&k_lds[s * KSTR + j * 4] = kb;
            float4 vv = ((const float4*)vp)[j];
            uint32_t v01 = cvt2(vv.x, vv.y);
            uint32_t v23 = cvt2(vv.z, vv.w);
            vt_lds[(j * 4 + 0) * VSTR + s] = (uint16_t)v01;
            vt_lds[(j * 4 + 1) * VSTR + s] = (uint16_t)(v01 >> 16);
            vt_lds[(j * 4 + 2) * VSTR + s] = (uint16_t)v23;
            vt_lds[(j * 4 + 3) * VSTR + s] = (uint16_t)(v23 >> 16);
        }
        for (int i = tid; i < 288; i += 256) w_lds[i] = conv_w[head * 288 + i];
        if (tid < 32) b_lds[tid] = conv_b[hc + tid];
    }
    __syncthreads();

    const f32x4 zero4 = {0.f, 0.f, 0.f, 0.f};

    // S^T MFMA batch for quarter QT into buffer S (4 tiles)
    #define SMFMA(S, QT) do {                                                              \
        __builtin_amdgcn_s_setprio(1);                                                     \
        _Pragma("unroll")                                                                  \
        for (int t = 0; t < 4; ++t) {                                                      \
            bf16x8 afrag = *(const bf16x8*)&k_lds[(((QT) * 4 + t) * 16 + l15) * KSTR + quad * 8]; \
            (S)[t] = __builtin_amdgcn_mfma_f32_16x16x32_bf16(afrag, qfrag, zero4, 0, 0, 0); \
        }                                                                                  \
        __builtin_amdgcn_s_setprio(0);                                                     \
    } while (0)

    // exp/pack + PV for quarter QT from buffer S
    #define EXPPV(S, QT) do {                                                              \
        uint32_t pkl[4], pkh[4];                                                           \
        _Pragma("unroll")                                                                  \
        for (int t = 0; t < 4; ++t) {                                                      \
            float p0 = __builtin_amdgcn_exp2f((S)[t][0]);                                  \
            float p1 = __builtin_amdgcn_exp2f((S)[t][1]);                                  \
            float p2 = __builtin_amdgcn_exp2f((S)[t][2]);                                  \
            float p3 = __builtin_amdgcn_exp2f((S)[t][3]);                                  \
            ss0 += p0; ss1 += p1; ss2 += p2; ss3 += p3;                                    \
            pkl[t] = cvt2(p0, p1);                                                         \
            pkh[t] = cvt2(p2, p3);                                                         \
        }                                                                                  \
        __builtin_amdgcn_s_setprio(1);                                                     \
        _Pragma("unroll")                                                                  \
        for (int c = 0; c < 2; ++c) {                                                      \
            uint32_t a0 = pkl[2 * c], a1 = pkl[2 * c + 1];                                 \
            uint32_t b0 = pkh[2 * c], b1 = pkh[2 * c + 1];                                 \
            asm("v_permlane32_swap_b32 %0, %1" : "+v"(a0), "+v"(a1));                      \
            asm("v_permlane32_swap_b32 %0, %1" : "+v"(b0), "+v"(b1));                      \
            asm("v_permlane16_swap_b32 %0, %1" : "+v"(a0), "+v"(a1));                      \
            asm("v_permlane16_swap_b32 %0, %1" : "+v"(b0), "+v"(b1));                      \
            u32x4 pv = {a0, b0, a1, b1};                                                   \
            bf16x8 pa = __builtin_bit_cast(bf16x8, pv);                                    \
            const int kb = ((QT) * 2 + c) * 32 + quad * 8;                                 \
            bf16x8 vb0 = *(const bf16x8*)&vt_lds[l15 * VSTR + kb];                         \
            accO[0] = __builtin_amdgcn_mfma_f32_16x16x32_bf16(pa, vb0, accO[0], 0, 0, 0);  \
            bf16x8 vb1 = *(const bf16x8*)&vt_lds[(16 + l15) * VSTR + kb];                  \
            accO[1] = __builtin_amdgcn_mfma_f32_16x16x32_bf16(pa, vb1, accO[1], 0, 0, 0);  \
        }                                                                                  \
        __builtin_amdgcn_s_setprio(0);                                                     \
    } while (0)

    // ---- Q software pipeline: load iteration 0 before the rolled loop ----
    float4 qA0, qA1;
    {
        const int  sq = (wave * 4 + 0) * 16 + l15;
        const long ql = base_l + (sq >> 3) * 32 + (sq & 7);
        const float* qp = qkv + (((long)b * 32768 + ql) * 256 + hc + quad * 8);
        qA0 = ((const float4*)qp)[0];
        qA1 = ((const float4*)qp)[1];
    }

    #pragma unroll 1   // ROLLED: keep per-iteration register peak only
    for (int it = 0; it < 4; ++it) {
        const int rt = wave * 4 + it;

        // ---- convert current Q (pre-scaled by SCALE*log2e), then prefetch next Q ----
        u32x4 qp4 = { cvt2(qA0.x * c1, qA0.y * c1), cvt2(qA0.z * c1, qA0.w * c1),
                      cvt2(qA1.x * c1, qA1.y * c1), cvt2(qA1.z * c1, qA1.w * c1) };
        const bf16x8 qfrag = __builtin_bit_cast(bf16x8, qp4);
        {
            const int  itn = (it < 3) ? it + 1 : 3;   // it=3 reloads (L2-hot, harmless)
            const int  sq  = (wave * 4 + itn) * 16 + l15;
            const long ql  = base_l + (sq >> 3) * 32 + (sq & 7);
            const float* qp = qkv + (((long)b * 32768 + ql) * 256 + hc + quad * 8);
            qA0 = ((const float4*)qp)[0];
            qA1 = ((const float4*)qp)[1];
        }

        f32x4 accO[2] = {zero4, zero4};
        float ss0 = 0.f, ss1 = 0.f, ss2 = 0.f, ss3 = 0.f;  // 4 independent sum chains

        // ---- 2-stage ping-pong across quarters: S(q+1) overlaps exp/PV(q) ----
        f32x4 sA[4], sB[4];
        SMFMA(sA, 0);
        #pragma unroll 1
        for (int qp_ = 0; qp_ < 2; ++qp_) {
            const int q0 = qp_ * 2, q1 = qp_ * 2 + 1;
            SMFMA(sB, q1);       // independent S tiles issue while PV(q0) drains below
            EXPPV(sA, q0);
            if (qp_ == 0) SMFMA(sA, 2);
            EXPPV(sB, q1);
        }

        // ---- softmax denominator reduce (all 256 keys seen) ----
        float ssum = (ss0 + ss1) + (ss2 + ss3);
        ssum += __shfl_xor(ssum, 16);
        ssum += __shfl_xor(ssum, 32);
        const float linv = __builtin_amdgcn_rcpf(ssum);
        // output row r of this lane is query quad*4+r; its sum lives at lane l15'=quad*4+r
        float linv4[4];
        #pragma unroll
        for (int r = 0; r < 4; ++r) linv4[r] = __shfl(linv, quad * 4 + r);

        // ---- epilogue: LePE (weights read from LDS here; not register-resident) + store ----
        const int hrow = rt * 2 + (quad >> 1);
        const int wsel = quad & 1;
        #pragma unroll
        for (int n = 0; n < 2; ++n) {
            const int d = n * 16 + l15;
            const float* wrow = &w_lds[(n * 16 + l15) * 9];
            float lep0, lep1, lep2, lep3;
            lep0 = lep1 = lep2 = lep3 = b_lds[n * 16 + l15];
            #pragma unroll
            for (int dy = 0; dy < 3; ++dy) {
                const int hh = hrow + dy - 1;
                float e0 = 0.f, e1 = 0.f, e2 = 0.f, e3 = 0.f, e4 = 0.f, e5 = 0.f;
                if (hh >= 0 && hh < 32) {
                    uint4 rv = *(const uint4*)&vt_lds[d * VSTR + hh * 8];
                    float c0 = bf2f_lo(rv.x), c1v = bf2f_hi(rv.x);
                    float c2 = bf2f_lo(rv.y), c3 = bf2f_hi(rv.y);
                    float c4 = bf2f_lo(rv.z), c5 = bf2f_hi(rv.z);
                    float c6 = bf2f_lo(rv.w), c7 = bf2f_hi(rv.w);
                    e0 = wsel ? c3 : 0.f;  e1 = wsel ? c4 : c0;
                    e2 = wsel ? c5 : c1v;  e3 = wsel ? c6 : c2;
                    e4 = wsel ? c7 : c3;   e5 = wsel ? 0.f : c4;
                }
                const float w0 = wrow[dy * 3 + 0];
                const float w1 = wrow[dy * 3 + 1];
                const float w2 = wrow[dy * 3 + 2];
                lep0 = fmaf(w0, e0, fmaf(w1, e1, fmaf(w2, e2, lep0)));
                lep1 = fmaf(w0, e1, fmaf(w1, e2, fmaf(w2, e3, lep1)));
                lep2 = fmaf(w0, e2, fmaf(w1, e3, fmaf(w2, e4, lep2)));
                lep3 = fmaf(w0, e3, fmaf(w1, e4, fmaf(w2, e5, lep3)));
            }
            const float lp[4] = {lep0, lep1, lep2, lep3};
            #pragma unroll
            for (int r = 0; r < 4; ++r) {
                const int s  = rt * 16 + quad * 4 + r;
                const int h  = s >> 3, w_ = s & 7;
                const long ol = base_l + h * 32 + w_;
                out[((long)b * 32768 + ol) * 256 + hc + d] = accO[n][r] * linv4[r] + lp[r];
            }
        }
    }
    #undef SMFMA
    #undef EXPPV
}

extern "C" void kernel_launch(void* const* d_in, const int* in_sizes, int n_in,
                              void* d_out, int out_size, void* d_ws, size_t ws_size,
                              hipStream_t stream)
{
    const float* qkv = (const float*)d_in[0];
    const float* cw  = (const float*)d_in[1];
    const float* cb  = (const float*)d_in[2];
    float* o = (float*)d_out;
    lepe_attn<<<2048, 256, 0, stream>>>(qkv, cw, cb, o);
}

// Round 11
// 319.275 us; speedup vs baseline: 1.1615x; 1.0028x over previous
//
#include <hip/hip_runtime.h>
#include <hip/hip_bf16.h>
#include <stdint.h>

// LePE windowed attention, MI355X gfx950. Round 15:
//  r14 (ping-pong reorder of same inst stream) = neutral -> reordering exhausted; attack the
//  instruction COUNT on the LDS/issue path instead. K fragments are identical across a wave's
//  4 query tiles, V fragments across query tiles too. Process TWO query tiles per iteration
//  (qfragA/qfragB): every k_lds/vt_lds ds_read_b128 feeds 2 MFMAs -> LDS reads HALVED
//  (128 -> 64 b128/wave), PV accO becomes 4 independent chains (A0,A1,B0,B1), and each MFMA
//  batch has an independent sibling stream to interleave with (dedup-driven ILP, not reorder).
//  Eighth-split rolled loops keep live regs small: acc = accS16+accOA8+accOB8 = 32, arch ~55
//  -> peak ~87 << 128, (256,4) safe (the r5/r7/r9 spill axis audited).
//  Numerics: key order and ssum chain mapping per query tile unchanged -> bit-identical.
//  Predicted: SQ_LDS_BANK_CONFLICT ~4.2M -> ~2.3M (fingerprint); FETCH/WRITE unchanged.
//  Kept from r13: raw v_exp_f32, XCD co-schedule swizzle, KSTR=40 pad, cvt_pk bf16, LePE in
//  epilogue from LDS, permlane P-exchange, setprio, (256,4) 4 blocks/CU.
// Inputs fp32: qkv (3,2,32768,256); conv_w (256,1,3,3); conv_b (256). Output fp32 (2,32768,256).
// Windows: H_SP=32, W_SP=8 -> 256 windows, S=256, heads=8, hd=32. Block per (window,head): grid 2048.

typedef short bf16x8 __attribute__((ext_vector_type(8)));
typedef float f32x4 __attribute__((ext_vector_type(4)));
typedef uint32_t u32x2 __attribute__((ext_vector_type(2)));
typedef uint32_t u32x4 __attribute__((ext_vector_type(4)));

#define KSTR 40    // K rows: 256 x 40 u16 (64B data + 16B pad -> bank-phase rotation 4*(5*row%8))
#define VSTR 264   // Vt rows: 32 x 264 (pad 8: bank rotation + b128 alignment)

__device__ __forceinline__ float bf2f_lo(uint32_t u) {
    union { uint32_t i; float f; } x; x.i = u << 16; return x.f;
}
__device__ __forceinline__ float bf2f_hi(uint32_t u) {
    union { uint32_t i; float f; } x; x.i = u & 0xffff0000u; return x.f;
}
// 2x f32 -> packed bf16 pair (lo=a, hi=b), RNE; compiles to v_cvt_pk_bf16_f32.
__device__ __forceinline__ uint32_t cvt2(float a, float b) {
    union { __hip_bfloat162 h; uint32_t u; } x;
    x.h = __float22bfloat162_rn(make_float2(a, b));
    return x.u;
}

__global__ __launch_bounds__(256, 4)
void lepe_attn(const float* __restrict__ qkv,
               const float* __restrict__ conv_w,
               const float* __restrict__ conv_b,
               float* __restrict__ out)
{
    __shared__ uint16_t k_lds[256 * KSTR];       // 20480 B
    __shared__ uint16_t vt_lds[32 * VSTR];       // 16896 B
    __shared__ float w_lds[288];                 //  1152 B
    __shared__ float b_lds[32];                  //   128 B  => total 38656 B (4x <= 160K)

    const int tid  = threadIdx.x;
    const int lane = tid & 63;
    const int wave = tid >> 6;
    const int l15  = lane & 15;
    const int quad = lane >> 4;

    // XCD co-schedule swizzle: blk = chunk*64 + head*8 + wlow; wid = chunk*8 + wlow.
    const int blk  = blockIdx.x;
    const int head = (blk >> 3) & 7;
    const int wid  = ((blk >> 6) << 3) | (blk & 7);
    const int b    = wid >> 7;
    const int rem  = wid & 127;
    const int dpt  = rem >> 2;
    const int nw   = rem & 3;

    const long base_l = (long)dpt * 1024 + nw * 8;
    const int  hc     = head * 32;

    const float c1 = 0.17677669529663687f * 1.4426950408889634f; // SCALE * log2(e)

    // ---- stage K [t][hd] bf16 (pad-40), V^T [hd][t] bf16, LePE weights fp32 ----
    {
        const int  s = tid;
        const long l = base_l + (s >> 3) * 32 + (s & 7);
        const float* kp = qkv + (((long)(2 + b) * 32768 + l) * 256 + hc);
        const float* vp = qkv + (((long)(4 + b) * 32768 + l) * 256 + hc);
        #pragma unroll
        for (int j = 0; j < 8; ++j) {
            float4 kv = ((const float4*)kp)[j];
            u32x2 kb = { cvt2(kv.x, kv.y), cvt2(kv.z, kv.w) };
            *(u32x2*)&k_lds[s * KSTR + j * 4] = kb;
            float4 vv = ((const float4*)vp)[j];
            uint32_t v01 = cvt2(vv.x, vv.y);
            uint32_t v23 = cvt2(vv.z, vv.w);
            vt_lds[(j * 4 + 0) * VSTR + s] = (uint16_t)v01;
            vt_lds[(j * 4 + 1) * VSTR + s] = (uint16_t)(v01 >> 16);
            vt_lds[(j * 4 + 2) * VSTR + s] = (uint16_t)v23;
            vt_lds[(j * 4 + 3) * VSTR + s] = (uint16_t)(v23 >> 16);
        }
        for (int i = tid; i < 288; i += 256) w_lds[i] = conv_w[head * 288 + i];
        if (tid < 32) b_lds[tid] = conv_b[hc + tid];
    }
    __syncthreads();

    const f32x4 zero4 = {0.f, 0.f, 0.f, 0.f};

    // epilogue for one query tile: softmax-normalize + LePE (weights from LDS) + store
    #define EPILOG(RT, ACCO, LINV4) do {                                                   \
        const int hrow = (RT) * 2 + (quad >> 1);                                           \
        const int wsel = quad & 1;                                                         \
        _Pragma("unroll")                                                                  \
        for (int n = 0; n < 2; ++n) {                                                      \
            const int d = n * 16 + l15;                                                    \
            const float* wrow = &w_lds[(n * 16 + l15) * 9];                                \
            float lep0, lep1, lep2, lep3;                                                  \
            lep0 = lep1 = lep2 = lep3 = b_lds[n * 16 + l15];                               \
            _Pragma("unroll")                                                              \
            for (int dy = 0; dy < 3; ++dy) {                                               \
                const int hh = hrow + dy - 1;                                              \
                float e0 = 0.f, e1 = 0.f, e2 = 0.f, e3 = 0.f, e4 = 0.f, e5 = 0.f;          \
                if (hh >= 0 && hh < 32) {                                                  \
                    uint4 rv = *(const uint4*)&vt_lds[d * VSTR + hh * 8];                  \
                    float c0 = bf2f_lo(rv.x), c1v = bf2f_hi(rv.x);                         \
                    float c2 = bf2f_lo(rv.y), c3 = bf2f_hi(rv.y);                          \
                    float c4 = bf2f_lo(rv.z), c5 = bf2f_hi(rv.z);                          \
                    float c6 = bf2f_lo(rv.w), c7 = bf2f_hi(rv.w);                          \
                    e0 = wsel ? c3 : 0.f;  e1 = wsel ? c4 : c0;                            \
                    e2 = wsel ? c5 : c1v;  e3 = wsel ? c6 : c2;                            \
                    e4 = wsel ? c7 : c3;   e5 = wsel ? 0.f : c4;                           \
                }                                                                          \
                const float w0 = wrow[dy * 3 + 0];                                         \
                const float w1 = wrow[dy * 3 + 1];                                         \
                const float w2 = wrow[dy * 3 + 2];                                         \
                lep0 = fmaf(w0, e0, fmaf(w1, e1, fmaf(w2, e2, lep0)));                     \
                lep1 = fmaf(w0, e1, fmaf(w1, e2, fmaf(w2, e3, lep1)));                     \
                lep2 = fmaf(w0, e2, fmaf(w1, e3, fmaf(w2, e4, lep2)));                     \
                lep3 = fmaf(w0, e3, fmaf(w1, e4, fmaf(w2, e5, lep3)));                     \
            }                                                                              \
            const float lp[4] = {lep0, lep1, lep2, lep3};                                  \
            _Pragma("unroll")                                                              \
            for (int r = 0; r < 4; ++r) {                                                  \
                const int s  = (RT) * 16 + quad * 4 + r;                                   \
                const int h  = s >> 3, w_ = s & 7;                                         \
                const long ol = base_l + h * 32 + w_;                                      \
                out[((long)b * 32768 + ol) * 256 + hc + d] = (ACCO)[n][r] * (LINV4)[r] + lp[r]; \
            }                                                                              \
        }                                                                                  \
    } while (0)

    #pragma unroll 1   // ROLLED pair loop: 2 query tiles (A,B) per iteration
    for (int itp = 0; itp < 2; ++itp) {
        const int rtA = wave * 4 + itp * 2;
        const int rtB = rtA + 1;

        // ---- Q loads for both tiles (L2/L3-hot) + convert (pre-scaled by SCALE*log2e) ----
        bf16x8 qfragA, qfragB;
        {
            const int  sqA = rtA * 16 + l15;
            const long qlA = base_l + (sqA >> 3) * 32 + (sqA & 7);
            const float* qpA = qkv + (((long)b * 32768 + qlA) * 256 + hc + quad * 8);
            float4 a0 = ((const float4*)qpA)[0];
            float4 a1 = ((const float4*)qpA)[1];
            const int  sqB = rtB * 16 + l15;
            const long qlB = base_l + (sqB >> 3) * 32 + (sqB & 7);
            const float* qpB = qkv + (((long)b * 32768 + qlB) * 256 + hc + quad * 8);
            float4 b0 = ((const float4*)qpB)[0];
            float4 b1 = ((const float4*)qpB)[1];
            u32x4 qa = { cvt2(a0.x * c1, a0.y * c1), cvt2(a0.z * c1, a0.w * c1),
                         cvt2(a1.x * c1, a1.y * c1), cvt2(a1.z * c1, a1.w * c1) };
            u32x4 qb = { cvt2(b0.x * c1, b0.y * c1), cvt2(b0.z * c1, b0.w * c1),
                         cvt2(b1.x * c1, b1.y * c1), cvt2(b1.z * c1, b1.w * c1) };
            qfragA = __builtin_bit_cast(bf16x8, qa);
            qfragB = __builtin_bit_cast(bf16x8, qb);
        }

        f32x4 accOA[2] = {zero4, zero4};
        f32x4 accOB[2] = {zero4, zero4};
        float ssA0 = 0.f, ssA1 = 0.f, ssA2 = 0.f, ssA3 = 0.f;
        float ssB0 = 0.f, ssB1 = 0.f, ssB2 = 0.f, ssB3 = 0.f;

        #pragma unroll 1   // eighth-split: 2 key tiles per step; each ds_read feeds 2 MFMAs
        for (int e = 0; e < 8; ++e) {
            const int t0 = e * 2, t1 = e * 2 + 1;
            bf16x8 afrag0 = *(const bf16x8*)&k_lds[(t0 * 16 + l15) * KSTR + quad * 8];
            bf16x8 afrag1 = *(const bf16x8*)&k_lds[(t1 * 16 + l15) * KSTR + quad * 8];
            __builtin_amdgcn_s_setprio(1);
            f32x4 sA0 = __builtin_amdgcn_mfma_f32_16x16x32_bf16(afrag0, qfragA, zero4, 0, 0, 0);
            f32x4 sB0 = __builtin_amdgcn_mfma_f32_16x16x32_bf16(afrag0, qfragB, zero4, 0, 0, 0);
            f32x4 sA1 = __builtin_amdgcn_mfma_f32_16x16x32_bf16(afrag1, qfragA, zero4, 0, 0, 0);
            f32x4 sB1 = __builtin_amdgcn_mfma_f32_16x16x32_bf16(afrag1, qfragB, zero4, 0, 0, 0);
            __builtin_amdgcn_s_setprio(0);

            // exp (raw v_exp_f32) + pack; same key order / chain mapping as before
            float pA00 = __builtin_amdgcn_exp2f(sA0[0]);
            float pA01 = __builtin_amdgcn_exp2f(sA0[1]);
            float pA02 = __builtin_amdgcn_exp2f(sA0[2]);
            float pA03 = __builtin_amdgcn_exp2f(sA0[3]);
            ssA0 += pA00; ssA1 += pA01; ssA2 += pA02; ssA3 += pA03;
            float pA10 = __builtin_amdgcn_exp2f(sA1[0]);
            float pA11 = __builtin_amdgcn_exp2f(sA1[1]);
            float pA12 = __builtin_amdgcn_exp2f(sA1[2]);
            float pA13 = __builtin_amdgcn_exp2f(sA1[3]);
            ssA0 += pA10; ssA1 += pA11; ssA2 += pA12; ssA3 += pA13;
            float pB00 = __builtin_amdgcn_exp2f(sB0[0]);
            float pB01 = __builtin_amdgcn_exp2f(sB0[1]);
            float pB02 = __builtin_amdgcn_exp2f(sB0[2]);
            float pB03 = __builtin_amdgcn_exp2f(sB0[3]);
            ssB0 += pB00; ssB1 += pB01; ssB2 += pB02; ssB3 += pB03;
            float pB10 = __builtin_amdgcn_exp2f(sB1[0]);
            float pB11 = __builtin_amdgcn_exp2f(sB1[1]);
            float pB12 = __builtin_amdgcn_exp2f(sB1[2]);
            float pB13 = __builtin_amdgcn_exp2f(sB1[3]);
            ssB0 += pB10; ssB1 += pB11; ssB2 += pB12; ssB3 += pB13;

            uint32_t a0 = cvt2(pA00, pA01), a1 = cvt2(pA10, pA11);
            uint32_t a2 = cvt2(pA02, pA03), a3 = cvt2(pA12, pA13);
            uint32_t b0 = cvt2(pB00, pB01), b1 = cvt2(pB10, pB11);
            uint32_t b2 = cvt2(pB02, pB03), b3 = cvt2(pB12, pB13);
            asm("v_permlane32_swap_b32 %0, %1" : "+v"(a0), "+v"(a1));
            asm("v_permlane32_swap_b32 %0, %1" : "+v"(a2), "+v"(a3));
            asm("v_permlane16_swap_b32 %0, %1" : "+v"(a0), "+v"(a1));
            asm("v_permlane16_swap_b32 %0, %1" : "+v"(a2), "+v"(a3));
            asm("v_permlane32_swap_b32 %0, %1" : "+v"(b0), "+v"(b1));
            asm("v_permlane32_swap_b32 %0, %1" : "+v"(b2), "+v"(b3));
            asm("v_permlane16_swap_b32 %0, %1" : "+v"(b0), "+v"(b1));
            asm("v_permlane16_swap_b32 %0, %1" : "+v"(b2), "+v"(b3));
            u32x4 pvA = {a0, a2, a1, a3};
            u32x4 pvB = {b0, b2, b1, b3};
            bf16x8 paA = __builtin_bit_cast(bf16x8, pvA);
            bf16x8 paB = __builtin_bit_cast(bf16x8, pvB);

            const int kb = e * 32 + quad * 8;
            bf16x8 vb0 = *(const bf16x8*)&vt_lds[l15 * VSTR + kb];
            bf16x8 vb1 = *(const bf16x8*)&vt_lds[(16 + l15) * VSTR + kb];
            __builtin_amdgcn_s_setprio(1);
            accOA[0] = __builtin_amdgcn_mfma_f32_16x16x32_bf16(paA, vb0, accOA[0], 0, 0, 0);
            accOB[0] = __builtin_amdgcn_mfma_f32_16x16x32_bf16(paB, vb0, accOB[0], 0, 0, 0);
            accOA[1] = __builtin_amdgcn_mfma_f32_16x16x32_bf16(paA, vb1, accOA[1], 0, 0, 0);
            accOB[1] = __builtin_amdgcn_mfma_f32_16x16x32_bf16(paB, vb1, accOB[1], 0, 0, 0);
            __builtin_amdgcn_s_setprio(0);
        }

        // ---- softmax denominator reduces (all 256 keys seen) ----
        float ssumA = (ssA0 + ssA1) + (ssA2 + ssA3);
        ssumA += __shfl_xor(ssumA, 16);
        ssumA += __shfl_xor(ssumA, 32);
        const float linvA = __builtin_amdgcn_rcpf(ssumA);
        float ssumB = (ssB0 + ssB1) + (ssB2 + ssB3);
        ssumB += __shfl_xor(ssumB, 16);
        ssumB += __shfl_xor(ssumB, 32);
        const float linvB = __builtin_amdgcn_rcpf(ssumB);
        float linvA4[4], linvB4[4];
        #pragma unroll
        for (int r = 0; r < 4; ++r) {
            linvA4[r] = __shfl(linvA, quad * 4 + r);
            linvB4[r] = __shfl(linvB, quad * 4 + r);
        }

        EPILOG(rtA, accOA, linvA4);
        EPILOG(rtB, accOB, linvB4);
    }
    #undef EPILOG
}

extern "C" void kernel_launch(void* const* d_in, const int* in_sizes, int n_in,
                              void* d_out, int out_size, void* d_ws, size_t ws_size,
                              hipStream_t stream)
{
    const float* qkv = (const float*)d_in[0];
    const float* cw  = (const float*)d_in[1];
    const float* cb  = (const float*)d_in[2];
    float* o = (float*)d_out;
    lepe_attn<<<2048, 256, 0, stream>>>(qkv, cw, cb, o);
}

// Round 12
// 318.188 us; speedup vs baseline: 1.1655x; 1.0034x over previous
//
#include <hip/hip_runtime.h>
#include <hip/hip_bf16.h>
#include <stdint.h>

// LePE windowed attention, MI355X gfx950. Round 16:
//  r14 (reorder) neutral, r15 (LDS dedup) neutral, r13 (VALU count cut) -11% => the lever on
//  this kernel is total VALU/trans instruction count (VALUBusy ~42%, only pipe >35%).
//  Change: softmax denominators via ONES-MFMA. The ssum reduction network (512 v_add_f32 +
//  12 shuffles + broadcasts per wave) computes row-sums of P = P x ones — a matmul. Ride it
//  on the 5%-utilized MFMA pipe: accSum = mfma(pa, ones, accSum) next to the PV MFMAs.
//  D[row=query quad*4+r] = sum_k P lands exactly where linv4[r] is needed: shuffles gone too,
//  replaced by 4 v_rcp per tile. Cost: 2 extra MFMAs/e-step + 8 AGPRs (acc 40, arch ~50 — safe).
//  Numerics: denominator = f32-MFMA sum of the SAME bf16 P values as the numerator (~2^-9
//  relative shift vs f32-add of pre-round p; tolerance 1.6e-2).
//  Kept from r15: 2-query-tile dedup (A/B), raw v_exp_f32, XCD co-schedule swizzle, KSTR=40,
//  cvt_pk bf16, permlane P-exchange, LePE epilogue from LDS, setprio, (256,4).
// Inputs fp32: qkv (3,2,32768,256); conv_w (256,1,3,3); conv_b (256). Output fp32 (2,32768,256).
// Windows: H_SP=32, W_SP=8 -> 256 windows, S=256, heads=8, hd=32. Block per (window,head): grid 2048.

typedef short bf16x8 __attribute__((ext_vector_type(8)));
typedef float f32x4 __attribute__((ext_vector_type(4)));
typedef uint32_t u32x2 __attribute__((ext_vector_type(2)));
typedef uint32_t u32x4 __attribute__((ext_vector_type(4)));

#define KSTR 40    // K rows: 256 x 40 u16 (64B data + 16B pad -> bank-phase rotation 4*(5*row%8))
#define VSTR 264   // Vt rows: 32 x 264 (pad 8: bank rotation + b128 alignment)

__device__ __forceinline__ float bf2f_lo(uint32_t u) {
    union { uint32_t i; float f; } x; x.i = u << 16; return x.f;
}
__device__ __forceinline__ float bf2f_hi(uint32_t u) {
    union { uint32_t i; float f; } x; x.i = u & 0xffff0000u; return x.f;
}
// 2x f32 -> packed bf16 pair (lo=a, hi=b), RNE; compiles to v_cvt_pk_bf16_f32.
__device__ __forceinline__ uint32_t cvt2(float a, float b) {
    union { __hip_bfloat162 h; uint32_t u; } x;
    x.h = __float22bfloat162_rn(make_float2(a, b));
    return x.u;
}

__global__ __launch_bounds__(256, 4)
void lepe_attn(const float* __restrict__ qkv,
               const float* __restrict__ conv_w,
               const float* __restrict__ conv_b,
               float* __restrict__ out)
{
    __shared__ uint16_t k_lds[256 * KSTR];       // 20480 B
    __shared__ uint16_t vt_lds[32 * VSTR];       // 16896 B
    __shared__ float w_lds[288];                 //  1152 B
    __shared__ float b_lds[32];                  //   128 B  => total 38656 B (4x <= 160K)

    const int tid  = threadIdx.x;
    const int lane = tid & 63;
    const int wave = tid >> 6;
    const int l15  = lane & 15;
    const int quad = lane >> 4;

    // XCD co-schedule swizzle: blk = chunk*64 + head*8 + wlow; wid = chunk*8 + wlow.
    const int blk  = blockIdx.x;
    const int head = (blk >> 3) & 7;
    const int wid  = ((blk >> 6) << 3) | (blk & 7);
    const int b    = wid >> 7;
    const int rem  = wid & 127;
    const int dpt  = rem >> 2;
    const int nw   = rem & 3;

    const long base_l = (long)dpt * 1024 + nw * 8;
    const int  hc     = head * 32;

    const float c1 = 0.17677669529663687f * 1.4426950408889634f; // SCALE * log2(e)

    // ---- stage K [t][hd] bf16 (pad-40), V^T [hd][t] bf16, LePE weights fp32 ----
    {
        const int  s = tid;
        const long l = base_l + (s >> 3) * 32 + (s & 7);
        const float* kp = qkv + (((long)(2 + b) * 32768 + l) * 256 + hc);
        const float* vp = qkv + (((long)(4 + b) * 32768 + l) * 256 + hc);
        #pragma unroll
        for (int j = 0; j < 8; ++j) {
            float4 kv = ((const float4*)kp)[j];
            u32x2 kb = { cvt2(kv.x, kv.y), cvt2(kv.z, kv.w) };
            *(u32x2*)&k_lds[s * KSTR + j * 4] = kb;
            float4 vv = ((const float4*)vp)[j];
            uint32_t v01 = cvt2(vv.x, vv.y);
            uint32_t v23 = cvt2(vv.z, vv.w);
            vt_lds[(j * 4 + 0) * VSTR + s] = (uint16_t)v01;
            vt_lds[(j * 4 + 1) * VSTR + s] = (uint16_t)(v01 >> 16);
            vt_lds[(j * 4 + 2) * VSTR + s] = (uint16_t)v23;
            vt_lds[(j * 4 + 3) * VSTR + s] = (uint16_t)(v23 >> 16);
        }
        for (int i = tid; i < 288; i += 256) w_lds[i] = conv_w[head * 288 + i];
        if (tid < 32) b_lds[tid] = conv_b[hc + tid];
    }
    __syncthreads();

    const f32x4 zero4 = {0.f, 0.f, 0.f, 0.f};
    // bf16 ones B-fragment for denominator MFMA (1.0 = 0x3F80)
    const u32x4 ones_u = {0x3F803F80u, 0x3F803F80u, 0x3F803F80u, 0x3F803F80u};
    const bf16x8 ones8 = __builtin_bit_cast(bf16x8, ones_u);

    // epilogue for one query tile: softmax-normalize + LePE (weights from LDS) + store
    #define EPILOG(RT, ACCO, LINV4) do {                                                   \
        const int hrow = (RT) * 2 + (quad >> 1);                                           \
        const int wsel = quad & 1;                                                         \
        _Pragma("unroll")                                                                  \
        for (int n = 0; n < 2; ++n) {                                                      \
            const int d = n * 16 + l15;                                                    \
            const float* wrow = &w_lds[(n * 16 + l15) * 9];                                \
            float lep0, lep1, lep2, lep3;                                                  \
            lep0 = lep1 = lep2 = lep3 = b_lds[n * 16 + l15];                               \
            _Pragma("unroll")                                                              \
            for (int dy = 0; dy < 3; ++dy) {                                               \
                const int hh = hrow + dy - 1;                                              \
                float e0 = 0.f, e1 = 0.f, e2 = 0.f, e3 = 0.f, e4 = 0.f, e5 = 0.f;          \
                if (hh >= 0 && hh < 32) {                                                  \
                    uint4 rv = *(const uint4*)&vt_lds[d * VSTR + hh * 8];                  \
                    float c0 = bf2f_lo(rv.x), c1v = bf2f_hi(rv.x);                         \
                    float c2 = bf2f_lo(rv.y), c3 = bf2f_hi(rv.y);                          \
                    float c4 = bf2f_lo(rv.z), c5 = bf2f_hi(rv.z);                          \
                    float c6 = bf2f_lo(rv.w), c7 = bf2f_hi(rv.w);                          \
                    e0 = wsel ? c3 : 0.f;  e1 = wsel ? c4 : c0;                            \
                    e2 = wsel ? c5 : c1v;  e3 = wsel ? c6 : c2;                            \
                    e4 = wsel ? c7 : c3;   e5 = wsel ? 0.f : c4;                           \
                }                                                                          \
                const float w0 = wrow[dy * 3 + 0];                                         \
                const float w1 = wrow[dy * 3 + 1];                                         \
                const float w2 = wrow[dy * 3 + 2];                                         \
                lep0 = fmaf(w0, e0, fmaf(w1, e1, fmaf(w2, e2, lep0)));                     \
                lep1 = fmaf(w0, e1, fmaf(w1, e2, fmaf(w2, e3, lep1)));                     \
                lep2 = fmaf(w0, e2, fmaf(w1, e3, fmaf(w2, e4, lep2)));                     \
                lep3 = fmaf(w0, e3, fmaf(w1, e4, fmaf(w2, e5, lep3)));                     \
            }                                                                              \
            const float lp[4] = {lep0, lep1, lep2, lep3};                                  \
            _Pragma("unroll")                                                              \
            for (int r = 0; r < 4; ++r) {                                                  \
                const int s  = (RT) * 16 + quad * 4 + r;                                   \
                const int h  = s >> 3, w_ = s & 7;                                         \
                const long ol = base_l + h * 32 + w_;                                      \
                out[((long)b * 32768 + ol) * 256 + hc + d] = (ACCO)[n][r] * (LINV4)[r] + lp[r]; \
            }                                                                              \
        }                                                                                  \
    } while (0)

    #pragma unroll 1   // ROLLED pair loop: 2 query tiles (A,B) per iteration
    for (int itp = 0; itp < 2; ++itp) {
        const int rtA = wave * 4 + itp * 2;
        const int rtB = rtA + 1;

        // ---- Q loads for both tiles (L2/L3-hot) + convert (pre-scaled by SCALE*log2e) ----
        bf16x8 qfragA, qfragB;
        {
            const int  sqA = rtA * 16 + l15;
            const long qlA = base_l + (sqA >> 3) * 32 + (sqA & 7);
            const float* qpA = qkv + (((long)b * 32768 + qlA) * 256 + hc + quad * 8);
            float4 a0 = ((const float4*)qpA)[0];
            float4 a1 = ((const float4*)qpA)[1];
            const int  sqB = rtB * 16 + l15;
            const long qlB = base_l + (sqB >> 3) * 32 + (sqB & 7);
            const float* qpB = qkv + (((long)b * 32768 + qlB) * 256 + hc + quad * 8);
            float4 b0 = ((const float4*)qpB)[0];
            float4 b1 = ((const float4*)qpB)[1];
            u32x4 qa = { cvt2(a0.x * c1, a0.y * c1), cvt2(a0.z * c1, a0.w * c1),
                         cvt2(a1.x * c1, a1.y * c1), cvt2(a1.z * c1, a1.w * c1) };
            u32x4 qb = { cvt2(b0.x * c1, b0.y * c1), cvt2(b0.z * c1, b0.w * c1),
                         cvt2(b1.x * c1, b1.y * c1), cvt2(b1.z * c1, b1.w * c1) };
            qfragA = __builtin_bit_cast(bf16x8, qa);
            qfragB = __builtin_bit_cast(bf16x8, qb);
        }

        f32x4 accOA[2] = {zero4, zero4};
        f32x4 accOB[2] = {zero4, zero4};
        f32x4 accSA = zero4, accSB = zero4;   // per-query denominators via ones-MFMA

        #pragma unroll 1   // eighth-split: 2 key tiles per step; each ds_read feeds 2 MFMAs
        for (int e = 0; e < 8; ++e) {
            const int t0 = e * 2, t1 = e * 2 + 1;
            bf16x8 afrag0 = *(const bf16x8*)&k_lds[(t0 * 16 + l15) * KSTR + quad * 8];
            bf16x8 afrag1 = *(const bf16x8*)&k_lds[(t1 * 16 + l15) * KSTR + quad * 8];
            __builtin_amdgcn_s_setprio(1);
            f32x4 sA0 = __builtin_amdgcn_mfma_f32_16x16x32_bf16(afrag0, qfragA, zero4, 0, 0, 0);
            f32x4 sB0 = __builtin_amdgcn_mfma_f32_16x16x32_bf16(afrag0, qfragB, zero4, 0, 0, 0);
            f32x4 sA1 = __builtin_amdgcn_mfma_f32_16x16x32_bf16(afrag1, qfragA, zero4, 0, 0, 0);
            f32x4 sB1 = __builtin_amdgcn_mfma_f32_16x16x32_bf16(afrag1, qfragB, zero4, 0, 0, 0);
            __builtin_amdgcn_s_setprio(0);

            // exp (raw v_exp_f32) + pack; NO scalar sum chains (denominator rides on MFMA)
            float pA00 = __builtin_amdgcn_exp2f(sA0[0]);
            float pA01 = __builtin_amdgcn_exp2f(sA0[1]);
            float pA02 = __builtin_amdgcn_exp2f(sA0[2]);
            float pA03 = __builtin_amdgcn_exp2f(sA0[3]);
            float pA10 = __builtin_amdgcn_exp2f(sA1[0]);
            float pA11 = __builtin_amdgcn_exp2f(sA1[1]);
            float pA12 = __builtin_amdgcn_exp2f(sA1[2]);
            float pA13 = __builtin_amdgcn_exp2f(sA1[3]);
            float pB00 = __builtin_amdgcn_exp2f(sB0[0]);
            float pB01 = __builtin_amdgcn_exp2f(sB0[1]);
            float pB02 = __builtin_amdgcn_exp2f(sB0[2]);
            float pB03 = __builtin_amdgcn_exp2f(sB0[3]);
            float pB10 = __builtin_amdgcn_exp2f(sB1[0]);
            float pB11 = __builtin_amdgcn_exp2f(sB1[1]);
            float pB12 = __builtin_amdgcn_exp2f(sB1[2]);
            float pB13 = __builtin_amdgcn_exp2f(sB1[3]);

            uint32_t a0 = cvt2(pA00, pA01), a1 = cvt2(pA10, pA11);
            uint32_t a2 = cvt2(pA02, pA03), a3 = cvt2(pA12, pA13);
            uint32_t b0 = cvt2(pB00, pB01), b1 = cvt2(pB10, pB11);
            uint32_t b2 = cvt2(pB02, pB03), b3 = cvt2(pB12, pB13);
            asm("v_permlane32_swap_b32 %0, %1" : "+v"(a0), "+v"(a1));
            asm("v_permlane32_swap_b32 %0, %1" : "+v"(a2), "+v"(a3));
            asm("v_permlane16_swap_b32 %0, %1" : "+v"(a0), "+v"(a1));
            asm("v_permlane16_swap_b32 %0, %1" : "+v"(a2), "+v"(a3));
            asm("v_permlane32_swap_b32 %0, %1" : "+v"(b0), "+v"(b1));
            asm("v_permlane32_swap_b32 %0, %1" : "+v"(b2), "+v"(b3));
            asm("v_permlane16_swap_b32 %0, %1" : "+v"(b0), "+v"(b1));
            asm("v_permlane16_swap_b32 %0, %1" : "+v"(b2), "+v"(b3));
            u32x4 pvA = {a0, a2, a1, a3};
            u32x4 pvB = {b0, b2, b1, b3};
            bf16x8 paA = __builtin_bit_cast(bf16x8, pvA);
            bf16x8 paB = __builtin_bit_cast(bf16x8, pvB);

            const int kb = e * 32 + quad * 8;
            bf16x8 vb0 = *(const bf16x8*)&vt_lds[l15 * VSTR + kb];
            bf16x8 vb1 = *(const bf16x8*)&vt_lds[(16 + l15) * VSTR + kb];
            __builtin_amdgcn_s_setprio(1);
            accOA[0] = __builtin_amdgcn_mfma_f32_16x16x32_bf16(paA, vb0, accOA[0], 0, 0, 0);
            accOB[0] = __builtin_amdgcn_mfma_f32_16x16x32_bf16(paB, vb0, accOB[0], 0, 0, 0);
            accOA[1] = __builtin_amdgcn_mfma_f32_16x16x32_bf16(paA, vb1, accOA[1], 0, 0, 0);
            accOB[1] = __builtin_amdgcn_mfma_f32_16x16x32_bf16(paB, vb1, accOB[1], 0, 0, 0);
            accSA    = __builtin_amdgcn_mfma_f32_16x16x32_bf16(paA, ones8, accSA, 0, 0, 0);
            accSB    = __builtin_amdgcn_mfma_f32_16x16x32_bf16(paB, ones8, accSB, 0, 0, 0);
            __builtin_amdgcn_s_setprio(0);
        }

        // ---- per-row inverse denominators: already in the right lane/register slots ----
        float linvA4[4], linvB4[4];
        #pragma unroll
        for (int r = 0; r < 4; ++r) {
            linvA4[r] = __builtin_amdgcn_rcpf(accSA[r]);
            linvB4[r] = __builtin_amdgcn_rcpf(accSB[r]);
        }

        EPILOG(rtA, accOA, linvA4);
        EPILOG(rtB, accOB, linvB4);
    }
    #undef EPILOG
}

extern "C" void kernel_launch(void* const* d_in, const int* in_sizes, int n_in,
                              void* d_out, int out_size, void* d_ws, size_t ws_size,
                              hipStream_t stream)
{
    const float* qkv = (const float*)d_in[0];
    const float* cw  = (const float*)d_in[1];
    const float* cb  = (const float*)d_in[2];
    float* o = (float*)d_out;
    lepe_attn<<<2048, 256, 0, stream>>>(qkv, cw, cb, o);
}

// Round 13
// 314.809 us; speedup vs baseline: 1.1780x; 1.0107x over previous
//
#include <hip/hip_runtime.h>
#include <hip/hip_bf16.h>
#include <stdint.h>

// LePE windowed attention, MI355X gfx950. Round 17:
//  r14/r15/r16 all null => the VALU blocks I shaved weren't the binding cost. VALUBusy=42%
//  implies ~6x my source census -> suspect the #pragma unroll 1 rolled loops (added only to
//  fit (256,4)'s 64-arch-VGPR cap) force per-iteration dynamic addressing + kill cross-step
//  ILP. r12 measured occupancy 4-vs-3 blocks = only ~3%. Undo the trade:
//  - (256,3): arch budget ~106 (r8 proved spill-free at full unroll).
//  - e-loop FULLY UNROLLED: ds addresses fold to base+immediate offset:N; cross-e-step ILP.
//  - LePE weights/bias hoisted to regs (r8 style); epilogue loses 72 LDS reads.
//  - Branchless LePE boundary: zero 3 row-weights (3 cndmask) instead of 6 taps + branch.
//  Kept: 2-query-tile dedup (r15), ones-MFMA denominators (r16), raw v_exp_f32 + XCD swizzle
//  (r13), KSTR=40 pad, cvt_pk bf16, permlane P-exchange, setprio.
//  Go/no-go: WRITE ~67MB (spill check). Neutral-or-worse => structure converged; write the
//  plateau constraint.
// Inputs fp32: qkv (3,2,32768,256); conv_w (256,1,3,3); conv_b (256). Output fp32 (2,32768,256).
// Windows: H_SP=32, W_SP=8 -> 256 windows, S=256, heads=8, hd=32. Block per (window,head): grid 2048.

typedef short bf16x8 __attribute__((ext_vector_type(8)));
typedef float f32x4 __attribute__((ext_vector_type(4)));
typedef uint32_t u32x2 __attribute__((ext_vector_type(2)));
typedef uint32_t u32x4 __attribute__((ext_vector_type(4)));

#define KSTR 40    // K rows: 256 x 40 u16 (64B data + 16B pad -> bank-phase rotation 4*(5*row%8))
#define VSTR 264   // Vt rows: 32 x 264 (pad 8: bank rotation + b128 alignment)

__device__ __forceinline__ float bf2f_lo(uint32_t u) {
    union { uint32_t i; float f; } x; x.i = u << 16; return x.f;
}
__device__ __forceinline__ float bf2f_hi(uint32_t u) {
    union { uint32_t i; float f; } x; x.i = u & 0xffff0000u; return x.f;
}
// 2x f32 -> packed bf16 pair (lo=a, hi=b), RNE; compiles to v_cvt_pk_bf16_f32.
__device__ __forceinline__ uint32_t cvt2(float a, float b) {
    union { __hip_bfloat162 h; uint32_t u; } x;
    x.h = __float22bfloat162_rn(make_float2(a, b));
    return x.u;
}

__global__ __launch_bounds__(256, 3)
void lepe_attn(const float* __restrict__ qkv,
               const float* __restrict__ conv_w,
               const float* __restrict__ conv_b,
               float* __restrict__ out)
{
    __shared__ uint16_t k_lds[256 * KSTR];       // 20480 B
    __shared__ uint16_t vt_lds[32 * VSTR];       // 16896 B
    __shared__ float w_lds[288];                 //  1152 B
    __shared__ float b_lds[32];                  //   128 B  => total 38656 B

    const int tid  = threadIdx.x;
    const int lane = tid & 63;
    const int wave = tid >> 6;
    const int l15  = lane & 15;
    const int quad = lane >> 4;

    // XCD co-schedule swizzle: blk = chunk*64 + head*8 + wlow; wid = chunk*8 + wlow.
    const int blk  = blockIdx.x;
    const int head = (blk >> 3) & 7;
    const int wid  = ((blk >> 6) << 3) | (blk & 7);
    const int b    = wid >> 7;
    const int rem  = wid & 127;
    const int dpt  = rem >> 2;
    const int nw   = rem & 3;

    const long base_l = (long)dpt * 1024 + nw * 8;
    const int  hc     = head * 32;

    const float c1 = 0.17677669529663687f * 1.4426950408889634f; // SCALE * log2(e)

    // ---- stage K [t][hd] bf16 (pad-40), V^T [hd][t] bf16, LePE weights fp32 ----
    {
        const int  s = tid;
        const long l = base_l + (s >> 3) * 32 + (s & 7);
        const float* kp = qkv + (((long)(2 + b) * 32768 + l) * 256 + hc);
        const float* vp = qkv + (((long)(4 + b) * 32768 + l) * 256 + hc);
        #pragma unroll
        for (int j = 0; j < 8; ++j) {
            float4 kv = ((const float4*)kp)[j];
            u32x2 kb = { cvt2(kv.x, kv.y), cvt2(kv.z, kv.w) };
            *(u32x2*)&k_lds[s * KSTR + j * 4] = kb;
            float4 vv = ((const float4*)vp)[j];
            uint32_t v01 = cvt2(vv.x, vv.y);
            uint32_t v23 = cvt2(vv.z, vv.w);
            vt_lds[(j * 4 + 0) * VSTR + s] = (uint16_t)v01;
            vt_lds[(j * 4 + 1) * VSTR + s] = (uint16_t)(v01 >> 16);
            vt_lds[(j * 4 + 2) * VSTR + s] = (uint16_t)v23;
            vt_lds[(j * 4 + 3) * VSTR + s] = (uint16_t)(v23 >> 16);
        }
        for (int i = tid; i < 288; i += 256) w_lds[i] = conv_w[head * 288 + i];
        if (tid < 32) b_lds[tid] = conv_b[hc + tid];
    }
    __syncthreads();

    // hoist this lane's LePE weights (channels l15 and 16+l15) — loop-invariant, fits (256,3)
    float wgt[18], bia[2];
    #pragma unroll
    for (int n = 0; n < 2; ++n) {
        #pragma unroll
        for (int i = 0; i < 9; ++i) wgt[n * 9 + i] = w_lds[(n * 16 + l15) * 9 + i];
        bia[n] = b_lds[n * 16 + l15];
    }

    const f32x4 zero4 = {0.f, 0.f, 0.f, 0.f};
    // bf16 ones B-fragment for denominator MFMA (1.0 = 0x3F80)
    const u32x4 ones_u = {0x3F803F80u, 0x3F803F80u, 0x3F803F80u, 0x3F803F80u};
    const bf16x8 ones8 = __builtin_bit_cast(bf16x8, ones_u);

    // epilogue for one query tile: softmax-normalize + LePE (branchless boundary) + store
    #define EPILOG(RT, ACCO, LINV4) do {                                                   \
        const int hrow = (RT) * 2 + (quad >> 1);                                           \
        const int wsel = quad & 1;                                                         \
        _Pragma("unroll")                                                                  \
        for (int n = 0; n < 2; ++n) {                                                      \
            const int d = n * 16 + l15;                                                    \
            float lep0, lep1, lep2, lep3;                                                  \
            lep0 = lep1 = lep2 = lep3 = bia[n];                                            \
            _Pragma("unroll")                                                              \
            for (int dy = 0; dy < 3; ++dy) {                                               \
                const int hh = hrow + dy - 1;                                              \
                const bool ok = (hh >= 0) && (hh < 32);                                    \
                const int hcl = ok ? hh : 0;                                               \
                uint4 rv = *(const uint4*)&vt_lds[d * VSTR + hcl * 8];                     \
                float c0 = bf2f_lo(rv.x), c1v = bf2f_hi(rv.x);                             \
                float c2 = bf2f_lo(rv.y), c3 = bf2f_hi(rv.y);                              \
                float c4 = bf2f_lo(rv.z), c5 = bf2f_hi(rv.z);                              \
                float c6 = bf2f_lo(rv.w), c7 = bf2f_hi(rv.w);                              \
                const float e0 = wsel ? c3 : 0.f;  const float e1 = wsel ? c4 : c0;        \
                const float e2 = wsel ? c5 : c1v;  const float e3 = wsel ? c6 : c2;        \
                const float e4 = wsel ? c7 : c3;   const float e5 = wsel ? 0.f : c4;       \
                const float w0 = ok ? wgt[n * 9 + dy * 3 + 0] : 0.f;                       \
                const float w1 = ok ? wgt[n * 9 + dy * 3 + 1] : 0.f;                       \
                const float w2 = ok ? wgt[n * 9 + dy * 3 + 2] : 0.f;                       \
                lep0 = fmaf(w0, e0, fmaf(w1, e1, fmaf(w2, e2, lep0)));                     \
                lep1 = fmaf(w0, e1, fmaf(w1, e2, fmaf(w2, e3, lep1)));                     \
                lep2 = fmaf(w0, e2, fmaf(w1, e3, fmaf(w2, e4, lep2)));                     \
                lep3 = fmaf(w0, e3, fmaf(w1, e4, fmaf(w2, e5, lep3)));                     \
            }                                                                              \
            const float lp[4] = {lep0, lep1, lep2, lep3};                                  \
            _Pragma("unroll")                                                              \
            for (int r = 0; r < 4; ++r) {                                                  \
                const int s  = (RT) * 16 + quad * 4 + r;                                   \
                const int h  = s >> 3, w_ = s & 7;                                         \
                const long ol = base_l + h * 32 + w_;                                      \
                out[((long)b * 32768 + ol) * 256 + hc + d] = (ACCO)[n][r] * (LINV4)[r] + lp[r]; \
            }                                                                              \
        }                                                                                  \
    } while (0)

    #pragma unroll 1   // ROLLED pair loop: 2 query tiles (A,B) per iteration
    for (int itp = 0; itp < 2; ++itp) {
        const int rtA = wave * 4 + itp * 2;
        const int rtB = rtA + 1;

        // ---- Q loads for both tiles (L2/L3-hot) + convert (pre-scaled by SCALE*log2e) ----
        bf16x8 qfragA, qfragB;
        {
            const int  sqA = rtA * 16 + l15;
            const long qlA = base_l + (sqA >> 3) * 32 + (sqA & 7);
            const float* qpA = qkv + (((long)b * 32768 + qlA) * 256 + hc + quad * 8);
            float4 a0 = ((const float4*)qpA)[0];
            float4 a1 = ((const float4*)qpA)[1];
            const int  sqB = rtB * 16 + l15;
            const long qlB = base_l + (sqB >> 3) * 32 + (sqB & 7);
            const float* qpB = qkv + (((long)b * 32768 + qlB) * 256 + hc + quad * 8);
            float4 b0 = ((const float4*)qpB)[0];
            float4 b1 = ((const float4*)qpB)[1];
            u32x4 qa = { cvt2(a0.x * c1, a0.y * c1), cvt2(a0.z * c1, a0.w * c1),
                         cvt2(a1.x * c1, a1.y * c1), cvt2(a1.z * c1, a1.w * c1) };
            u32x4 qb = { cvt2(b0.x * c1, b0.y * c1), cvt2(b0.z * c1, b0.w * c1),
                         cvt2(b1.x * c1, b1.y * c1), cvt2(b1.z * c1, b1.w * c1) };
            qfragA = __builtin_bit_cast(bf16x8, qa);
            qfragB = __builtin_bit_cast(bf16x8, qb);
        }

        f32x4 accOA[2] = {zero4, zero4};
        f32x4 accOB[2] = {zero4, zero4};
        f32x4 accSA = zero4, accSB = zero4;   // per-query denominators via ones-MFMA

        // shared LDS bases: e-loop unrolled -> all ds offsets fold to base + immediate
        const uint16_t* kbase = &k_lds[l15 * KSTR + quad * 8];
        const uint16_t* vbase = &vt_lds[l15 * VSTR + quad * 8];

        #pragma unroll   // FULLY UNROLLED: immediate ds offsets + cross-e-step ILP
        for (int e = 0; e < 8; ++e) {
            bf16x8 afrag0 = *(const bf16x8*)&kbase[(e * 2 + 0) * 16 * KSTR];
            bf16x8 afrag1 = *(const bf16x8*)&kbase[(e * 2 + 1) * 16 * KSTR];
            __builtin_amdgcn_s_setprio(1);
            f32x4 sA0 = __builtin_amdgcn_mfma_f32_16x16x32_bf16(afrag0, qfragA, zero4, 0, 0, 0);
            f32x4 sB0 = __builtin_amdgcn_mfma_f32_16x16x32_bf16(afrag0, qfragB, zero4, 0, 0, 0);
            f32x4 sA1 = __builtin_amdgcn_mfma_f32_16x16x32_bf16(afrag1, qfragA, zero4, 0, 0, 0);
            f32x4 sB1 = __builtin_amdgcn_mfma_f32_16x16x32_bf16(afrag1, qfragB, zero4, 0, 0, 0);
            __builtin_amdgcn_s_setprio(0);

            // exp (raw v_exp_f32) + pack; denominator rides on MFMA (no scalar chains)
            float pA00 = __builtin_amdgcn_exp2f(sA0[0]);
            float pA01 = __builtin_amdgcn_exp2f(sA0[1]);
            float pA02 = __builtin_amdgcn_exp2f(sA0[2]);
            float pA03 = __builtin_amdgcn_exp2f(sA0[3]);
            float pA10 = __builtin_amdgcn_exp2f(sA1[0]);
            float pA11 = __builtin_amdgcn_exp2f(sA1[1]);
            float pA12 = __builtin_amdgcn_exp2f(sA1[2]);
            float pA13 = __builtin_amdgcn_exp2f(sA1[3]);
            float pB00 = __builtin_amdgcn_exp2f(sB0[0]);
            float pB01 = __builtin_amdgcn_exp2f(sB0[1]);
            float pB02 = __builtin_amdgcn_exp2f(sB0[2]);
            float pB03 = __builtin_amdgcn_exp2f(sB0[3]);
            float pB10 = __builtin_amdgcn_exp2f(sB1[0]);
            float pB11 = __builtin_amdgcn_exp2f(sB1[1]);
            float pB12 = __builtin_amdgcn_exp2f(sB1[2]);
            float pB13 = __builtin_amdgcn_exp2f(sB1[3]);

            uint32_t a0 = cvt2(pA00, pA01), a1 = cvt2(pA10, pA11);
            uint32_t a2 = cvt2(pA02, pA03), a3 = cvt2(pA12, pA13);
            uint32_t b0 = cvt2(pB00, pB01), b1 = cvt2(pB10, pB11);
            uint32_t b2 = cvt2(pB02, pB03), b3 = cvt2(pB12, pB13);
            asm("v_permlane32_swap_b32 %0, %1" : "+v"(a0), "+v"(a1));
            asm("v_permlane32_swap_b32 %0, %1" : "+v"(a2), "+v"(a3));
            asm("v_permlane16_swap_b32 %0, %1" : "+v"(a0), "+v"(a1));
            asm("v_permlane16_swap_b32 %0, %1" : "+v"(a2), "+v"(a3));
            asm("v_permlane32_swap_b32 %0, %1" : "+v"(b0), "+v"(b1));
            asm("v_permlane32_swap_b32 %0, %1" : "+v"(b2), "+v"(b3));
            asm("v_permlane16_swap_b32 %0, %1" : "+v"(b0), "+v"(b1));
            asm("v_permlane16_swap_b32 %0, %1" : "+v"(b2), "+v"(b3));
            u32x4 pvA = {a0, a2, a1, a3};
            u32x4 pvB = {b0, b2, b1, b3};
            bf16x8 paA = __builtin_bit_cast(bf16x8, pvA);
            bf16x8 paB = __builtin_bit_cast(bf16x8, pvB);

            bf16x8 vb0 = *(const bf16x8*)&vbase[e * 32];
            bf16x8 vb1 = *(const bf16x8*)&vbase[16 * VSTR + e * 32];
            __builtin_amdgcn_s_setprio(1);
            accOA[0] = __builtin_amdgcn_mfma_f32_16x16x32_bf16(paA, vb0, accOA[0], 0, 0, 0);
            accOB[0] = __builtin_amdgcn_mfma_f32_16x16x32_bf16(paB, vb0, accOB[0], 0, 0, 0);
            accOA[1] = __builtin_amdgcn_mfma_f32_16x16x32_bf16(paA, vb1, accOA[1], 0, 0, 0);
            accOB[1] = __builtin_amdgcn_mfma_f32_16x16x32_bf16(paB, vb1, accOB[1], 0, 0, 0);
            accSA    = __builtin_amdgcn_mfma_f32_16x16x32_bf16(paA, ones8, accSA, 0, 0, 0);
            accSB    = __builtin_amdgcn_mfma_f32_16x16x32_bf16(paB, ones8, accSB, 0, 0, 0);
            __builtin_amdgcn_s_setprio(0);
        }

        // ---- per-row inverse denominators: already in the right lane/register slots ----
        float linvA4[4], linvB4[4];
        #pragma unroll
        for (int r = 0; r < 4; ++r) {
            linvA4[r] = __builtin_amdgcn_rcpf(accSA[r]);
            linvB4[r] = __builtin_amdgcn_rcpf(accSB[r]);
        }

        EPILOG(rtA, accOA, linvA4);
        EPILOG(rtB, accOB, linvB4);
    }
    #undef EPILOG
}

extern "C" void kernel_launch(void* const* d_in, const int* in_sizes, int n_in,
                              void* d_out, int out_size, void* d_ws, size_t ws_size,
                              hipStream_t stream)
{
    const float* qkv = (const float*)d_in[0];
    const float* cw  = (const float*)d_in[1];
    const float* cb  = (const float*)d_in[2];
    float* o = (float*)d_out;
    lepe_attn<<<2048, 256, 0, stream>>>(qkv, cw, cb, o);
}